// Round 11
// baseline (295.872 us; speedup 1.0000x reference)
//
#include <hip/hip_runtime.h>
#include <hip/hip_fp16.h>

// GAT regression: 2-layer GAT + linear head.
// R18: CSR build replaced — the bucketed 2-level sort (LDS-atomic histograms,
//      ~33-way same-address contention in csr_build) becomes a flat global-
//      atomic counting sort: hist(atomicAdd cnt[dst]) -> bsum -> scan196 ->
//      offs(block scans) -> scatter(atomicAdd cur[dst], write src).
//      epair shrunk to u16 (only src is ever consumed; dst implicit in row).
// R17 retained: gemm2 deleted (projection vectors fused into agg1 epilogue),
//      MFMA gemm1 with LDS-staged A, fp8 e4m3 H1 rows, in-agg softmax weights,
//      scalar agg2 on the (logit,s) table.
// Requires N < 65536 (16-bit packing). N = 50000.

#define LEAKY(x) ((x) > 0.f ? (x) : 0.2f * (x))

typedef float v2f __attribute__((ext_vector_type(2)));
typedef _Float16 f16x8 __attribute__((ext_vector_type(8)));
typedef __fp16 h16x2 __attribute__((ext_vector_type(2)));
typedef float f32x4 __attribute__((ext_vector_type(4)));

// ---------------- flat counting-sort CSR build ----------------

template <int VPT>
__global__ __launch_bounds__(256) void hist_kernel(const int* __restrict__ ei, int E, int n,
                                                   int* __restrict__ cnt) {
  int base = blockIdx.x * (256 * VPT) + threadIdx.x;
  int tot = E + n;
#pragma unroll
  for (int u = 0; u < VPT; ++u) {
    int i = base + u * 256;
    if (i < tot) {
      int d = (i < E) ? ei[E + i] : (i - E);
      atomicAdd(&cnt[d], 1);
    }
  }
}

__global__ __launch_bounds__(256) void bsum_kernel(const int* __restrict__ cnt,
                                                   int* __restrict__ bsum, int n) {
  __shared__ int sm[256];
  int t = threadIdx.x;
  int d = blockIdx.x * 256 + t;
  sm[t] = (d < n) ? cnt[d] : 0;
  __syncthreads();
  for (int s = 128; s > 0; s >>= 1) {
    if (t < s) sm[t] += sm[t + s];
    __syncthreads();
  }
  if (t == 0) bsum[blockIdx.x] = sm[0];
}

__global__ __launch_bounds__(256) void scan196_kernel(const int* __restrict__ bsum,
                                                      int* __restrict__ bbase, int B) {
  __shared__ int sm[256];
  int t = threadIdx.x;
  int v = (t < B) ? bsum[t] : 0;
  sm[t] = v;
  __syncthreads();
  for (int s = 1; s < 256; s <<= 1) {
    int a = (t >= s) ? sm[t - s] : 0;
    __syncthreads();
    sm[t] += a;
    __syncthreads();
  }
  if (t < B) bbase[t] = sm[t] - v;
}

__global__ __launch_bounds__(256) void offs_kernel(const int* __restrict__ cnt,
                                                   const int* __restrict__ bbase,
                                                   int* __restrict__ off,
                                                   int* __restrict__ cur, int n, int Etot) {
  __shared__ int sm[256];
  int t = threadIdx.x;
  int d = blockIdx.x * 256 + t;
  int v = (d < n) ? cnt[d] : 0;
  sm[t] = v;
  __syncthreads();
  for (int s = 1; s < 256; s <<= 1) {
    int a = (t >= s) ? sm[t - s] : 0;
    __syncthreads();
    sm[t] += a;
    __syncthreads();
  }
  int pos = bbase[blockIdx.x] + sm[t] - v;
  if (d < n) {
    off[d] = pos;
    cur[d] = pos;
  }
  if (d == n) off[n] = Etot;
}

template <int VPT>
__global__ __launch_bounds__(256) void scatter_kernel(const int* __restrict__ ei, int E, int n,
                                                      int* __restrict__ cur,
                                                      unsigned short* __restrict__ eps) {
  int base = blockIdx.x * (256 * VPT) + threadIdx.x;
  int tot = E + n;
#pragma unroll
  for (int u = 0; u < VPT; ++u) {
    int i = base + u * 256;
    if (i < tot) {
      int s, d;
      if (i < E) { s = ei[i]; d = ei[E + i]; }
      else       { s = d = i - E; }
      int p = atomicAdd(&cur[d], 1);
      eps[p] = (unsigned short)s;
    }
  }
}

// ---------------- W prep: W1 fragment pack + layer-2 projection vectors -----

// W1 pack: element e = (((cn*4+kk)*4+g)*16+c)*8+i  stores W1[kk*32+g*8+i][cn*16+c]
// v-vectors: v_src2[k]=W2[k,:]·a_src2, v_dst2[k]=W2[k,:]·a_dst2, v_lin[k]=W2[k,:]·lin_w
__global__ __launch_bounds__(256) void wprep_kernel(const float* __restrict__ W1,
                                                    const float* __restrict__ W2,
                                                    const float* __restrict__ as2,
                                                    const float* __restrict__ ad2,
                                                    const float* __restrict__ lw,
                                                    unsigned short* __restrict__ Wp1,
                                                    float* __restrict__ vsrc2,
                                                    float* __restrict__ vdst2,
                                                    float* __restrict__ vlin) {
  int t = blockIdx.x * 256 + threadIdx.x;
  if (t < 16384) {
    int e = t;
    int i = e & 7;
    int c = (e >> 3) & 15;
    int g = (e >> 7) & 3;
    int kk = (e >> 9) & 3;
    int cn = e >> 11;
    int k = kk * 32 + g * 8 + i;
    int col = cn * 16 + c;
    __half h = __float2half(W1[k * 128 + col]);
    Wp1[e] = *(unsigned short*)&h;
  } else if (t < 16384 + 128) {
    int k = t - 16384;
    float a = 0.f, b = 0.f, s = 0.f;
    for (int cc = 0; cc < 64; ++cc) {
      float w = W2[k * 64 + cc];
      a = fmaf(w, as2[cc], a);
      b = fmaf(w, ad2[cc], b);
      s = fmaf(w, lw[cc], s);
    }
    vsrc2[k] = a;
    vdst2[k] = b;
    vlin[k] = s;
  }
}

// ---------------- MFMA GEMM1 + logits (LDS-staged A) ----------------

// block = 4 waves = 2M x 2N(head); 32 rows, N=128, H out fp8 e4m3.
__global__ __launch_bounds__(256) void gemm1_kernel(const float* __restrict__ X,
                                                    const uint4* __restrict__ Wp,
                                                    const float* __restrict__ a_src,
                                                    const float* __restrict__ a_dst,
                                                    unsigned char* __restrict__ Hout,
                                                    float2* __restrict__ als,
                                                    float2* __restrict__ ald, int n) {
  __shared__ float Xl[32 * 132];      // 32 rows x 128 f32, +4 pad (bank-friendly)
  __shared__ float lgt[2][2][2][16];  // [wm][head][src/dst][row]
  int t = threadIdx.x;
  int wave = t >> 6, lane = t & 63;
  int wm = wave >> 1, wn = wave & 1;
  int g = lane >> 4, c = lane & 15;
  int nb0 = blockIdx.x * 32;

  // ---- stage 32 rows coalesced (float4), padded rows of 132 floats ----
  {
    const float4* Xg = (const float4*)X;
    float4* Xs = (float4*)Xl;
#pragma unroll
    for (int u = 0; u < 4; ++u) {
      int idx = u * 256 + t;          // 0..1023 float4 slots
      int r = idx >> 5, c4 = idx & 31;
      int row = nb0 + r;
      int rc = row < n ? row : (n - 1);
      Xs[r * 33 + c4] = Xg[(size_t)rc * 32 + c4];
    }
  }
  __syncthreads();

  // ---- A fragments from LDS: row = wm*16+c, k = g*8 + i (+32*kk) ----
  f16x8 af[4];
  const float* xr = Xl + (wm * 16 + c) * 132 + g * 8;
#pragma unroll
  for (int kk = 0; kk < 4; ++kk) {
    float4 x0 = *(const float4*)(xr + kk * 32);
    float4 x1 = *(const float4*)(xr + kk * 32 + 4);
    union { f16x8 v; h16x2 p[4]; } A;
    A.p[0] = __builtin_amdgcn_cvt_pkrtz(x0.x, x0.y);
    A.p[1] = __builtin_amdgcn_cvt_pkrtz(x0.z, x0.w);
    A.p[2] = __builtin_amdgcn_cvt_pkrtz(x1.x, x1.y);
    A.p[3] = __builtin_amdgcn_cvt_pkrtz(x1.z, x1.w);
    af[kk] = A.v;
  }

  // ---- MFMA: 4 col-tiles x 4 k-steps ----
  f32x4 acc[4];
  f32x4 z = {0.f, 0.f, 0.f, 0.f};
#pragma unroll
  for (int cn = 0; cn < 4; ++cn) acc[cn] = z;
#pragma unroll
  for (int cn = 0; cn < 4; ++cn) {
    int cng = wn * 4 + cn;
#pragma unroll
    for (int kk = 0; kk < 4; ++kk) {
      union { uint4 u; f16x8 v; } B;
      B.u = Wp[(cng * 4 + kk) * 64 + lane];
      acc[cn] = __builtin_amdgcn_mfma_f32_16x16x32_f16(af[kk], B.v, acc[cn], 0, 0, 0);
    }
  }

  // ---- epilogue: fp8 H store + logit dots ----
  float asv[4], adv[4];
#pragma unroll
  for (int cn = 0; cn < 4; ++cn) {
    int col_l = wn * 64 + cn * 16 + c;
    asv[cn] = a_src[col_l];
    adv[cn] = a_dst[col_l];
  }
  float ps[4] = {0.f, 0.f, 0.f, 0.f};
  float pd[4] = {0.f, 0.f, 0.f, 0.f};
#pragma unroll
  for (int cn = 0; cn < 4; ++cn) {
#pragma unroll
    for (int r = 0; r < 4; ++r) {
      float v = acc[cn][r];
      ps[r] = fmaf(v, asv[cn], ps[r]);
      pd[r] = fmaf(v, adv[cn], pd[r]);
      int noder = nb0 + wm * 16 + g * 4 + r;
      int colg = wn * 64 + cn * 16 + c;
      if (noder < n) {
        int b8 = __builtin_amdgcn_cvt_pk_fp8_f32(v, v, 0, false);
        Hout[(size_t)noder * 128 + colg] = (unsigned char)(b8 & 0xff);
      }
    }
  }
#pragma unroll
  for (int r = 0; r < 4; ++r) {
#pragma unroll
    for (int m = 1; m <= 8; m <<= 1) {
      ps[r] += __shfl_xor(ps[r], m, 64);
      pd[r] += __shfl_xor(pd[r], m, 64);
    }
  }
  if (c == 0) {
#pragma unroll
    for (int r = 0; r < 4; ++r) {
      lgt[wm][wn][0][g * 4 + r] = ps[r];
      lgt[wm][wn][1][g * 4 + r] = pd[r];
    }
  }
  __syncthreads();
  if (t < 32) {
    int wmm = t >> 4, row = t & 15;
    int node = nb0 + wmm * 16 + row;
    if (node < n) {
      als[node] = make_float2(lgt[wmm][0][0][row], lgt[wmm][1][0][row]);
      ald[node] = make_float2(lgt[wmm][0][1][row], lgt[wmm][1][1][row]);
    }
  }
}

// ---------------- aggregation ----------------

// layer 1 (fp8 rows, 128B) + fused layer-2 projection epilogue.
__global__ __launch_bounds__(256) void agg1_kernel(const unsigned char* __restrict__ Hb8,
                                                   const float2* __restrict__ als,
                                                   const float2* __restrict__ ald,
                                                   const unsigned short* __restrict__ eps,
                                                   const int* __restrict__ off,
                                                   const float* __restrict__ b1,
                                                   const float* __restrict__ vsrc2,
                                                   const float* __restrict__ vdst2,
                                                   const float* __restrict__ vlin,
                                                   float2* __restrict__ gsrc,
                                                   float* __restrict__ adst2, int n) {
  __shared__ float wlds[4][128];
  int wid = (blockIdx.x * 256 + threadIdx.x) >> 6;
  int lane = threadIdx.x & 63;
  if (wid >= n) return;
  wid = __builtin_amdgcn_readfirstlane(wid);
  int wslot = (threadIdx.x >> 6) & 3;
  int half = lane >> 5;
  int k0 = off[wid], k1 = off[wid + 1];
  const unsigned short* Hu = (const unsigned short*)Hb8;
  float2 advv = ald[wid];
  float* wrow = &wlds[wslot][half << 6];

  float ax = 0.f, ay = 0.f, den = 0.f;

  for (int kb = k0; kb < k1; kb += 64) {
    int rem = min(k1 - kb, 64);
    int e = kb + (lane < rem ? lane : rem - 1);
    unsigned pp = eps[e];
    float2 l = als[pp];
    float g0 = __expf(LEAKY(l.x + advv.x));
    float g1 = __expf(LEAKY(l.y + advv.y));
    wlds[wslot][lane] = g0;
    wlds[wslot][64 + lane] = g1;

#define EDGE1(jj)                                                                   \
  {                                                                                 \
    unsigned p = (unsigned)__builtin_amdgcn_readlane((int)pp, (jj));                \
    float w = wrow[(jj)];                                                           \
    unsigned short hv = Hu[(p << 6) | (unsigned)lane];                              \
    v2f hf = __builtin_amdgcn_cvt_pk_f32_fp8((int)hv, false);                       \
    den += w;                                                                       \
    ax = fmaf(hf.x, w, ax);                                                         \
    ay = fmaf(hf.y, w, ay);                                                         \
  }

    int nb = rem >> 3;
    for (int b = 0; b < nb; ++b) {
      int jb = b << 3;
#pragma unroll
      for (int j = 0; j < 8; ++j) EDGE1(jb + j);
    }
    for (int jj = nb << 3; jj < rem; ++jj) EDGE1(jj);
#undef EDGE1
  }

  // elu(out + b1), then project onto the three layer-2 vectors.
  float inv = 1.f / (den + 1e-16f);
  float2 bv = ((const float2*)b1)[lane];
  float r0 = ax * inv + bv.x;
  float r1 = ay * inv + bv.y;
  r0 = r0 > 0.f ? r0 : (__expf(r0) - 1.f);
  r1 = r1 > 0.f ? r1 : (__expf(r1) - 1.f);
  float2 vs = ((const float2*)vsrc2)[lane];
  float2 vd = ((const float2*)vdst2)[lane];
  float2 vl = ((const float2*)vlin)[lane];
  float ps = r0 * vs.x + r1 * vs.y;
  float pd = r0 * vd.x + r1 * vd.y;
  float sv = r0 * vl.x + r1 * vl.y;
#pragma unroll
  for (int m = 1; m <= 32; m <<= 1) {
    ps += __shfl_xor(ps, m, 64);
    pd += __shfl_xor(pd, m, 64);
    sv += __shfl_xor(sv, m, 64);
  }
  if (lane == 0) {
    gsrc[wid] = make_float2(ps, sv);
    adst2[wid] = pd;
  }
}

// layer 2 + head, collapsed: per edge gather (logit_src, s) float2; scalar agg.
__global__ __launch_bounds__(256) void agg2_kernel(const float2* __restrict__ gsrc,
                                                   const float* __restrict__ adst2,
                                                   const unsigned short* __restrict__ eps,
                                                   const int* __restrict__ off,
                                                   const float* __restrict__ b2,
                                                   const float* __restrict__ lin_w,
                                                   const float* __restrict__ lin_b,
                                                   float* __restrict__ out, int n) {
  int wid = (blockIdx.x * 256 + threadIdx.x) >> 6;
  int lane = threadIdx.x & 63;
  if (wid >= n) return;
  wid = __builtin_amdgcn_readfirstlane(wid);
  int k0 = off[wid], k1 = off[wid + 1];
  float adv = adst2[wid];

  float num = 0.f, den = 0.f;
  for (int kb = k0; kb < k1; kb += 64) {
    int e = kb + lane;
    bool ok = e < k1;
    unsigned pp = eps[ok ? e : k0];
    float2 g = gsrc[pp];
    float w = ok ? __expf(LEAKY(g.x + adv)) : 0.f;
    num = fmaf(w, g.y, num);
    den += w;
  }
  float bt = b2[lane] * lin_w[lane];  // lanes cover all 64 ch -> b2.lin_w
#pragma unroll
  for (int m = 1; m <= 32; m <<= 1) {
    num += __shfl_xor(num, m, 64);
    den += __shfl_xor(den, m, 64);
    bt  += __shfl_xor(bt, m, 64);
  }
  if (lane == 0) out[wid] = num / (den + 1e-16f) + bt + lin_b[0];
}

// ---------------- launcher ----------------

static inline size_t alignup(size_t v) { return (v + 255) & ~(size_t)255; }

extern "C" void kernel_launch(void* const* d_in, const int* in_sizes, int n_in,
                              void* d_out, int out_size, void* d_ws, size_t ws_size,
                              hipStream_t stream) {
  const float* x   = (const float*)d_in[0];
  const int*   ei  = (const int*)d_in[1];
  const float* W1  = (const float*)d_in[2];
  const float* as1 = (const float*)d_in[3];
  const float* ad1 = (const float*)d_in[4];
  const float* b1  = (const float*)d_in[5];
  const float* W2  = (const float*)d_in[6];
  const float* as2 = (const float*)d_in[7];
  const float* ad2 = (const float*)d_in[8];
  const float* b2  = (const float*)d_in[9];
  const float* lw  = (const float*)d_in[10];
  const float* lb  = (const float*)d_in[11];
  float* out = (float*)d_out;

  const int N = out_size;          // 50000
  const int E = in_sizes[1] / 2;   // 1600000
  const int Etot = E + N;
  const int B = (N + 255) >> 8;    // 196 scan blocks

  char* p = (char*)d_ws;
  int* cnt  = (int*)p;  p += alignup((size_t)N * 4);
  int* bsum = (int*)p;  p += alignup((size_t)(B + 1) * 4);
  int* bbase= (int*)p;  p += alignup((size_t)(B + 1) * 4);
  int* off  = (int*)p;  p += alignup((size_t)(N + 1) * 4);
  int* cur  = (int*)p;  p += alignup((size_t)N * 4);
  unsigned short* eps = (unsigned short*)p; p += alignup((size_t)Etot * 2);
  float2* als = (float2*)p; p += alignup((size_t)N * 8);
  float2* ald = (float2*)p; p += alignup((size_t)N * 8);
  float2* gsrc = (float2*)p; p += alignup((size_t)N * 8);
  float* adst2 = (float*)p; p += alignup((size_t)N * 4);
  unsigned char* h1b = (unsigned char*)p; p += alignup((size_t)N * 128);
  unsigned short* wp1 = (unsigned short*)p; p += alignup((size_t)16384 * 2);
  float* vsrc2 = (float*)p; p += alignup((size_t)128 * 4);
  float* vdst2 = (float*)p; p += alignup((size_t)128 * 4);
  float* vlin  = (float*)p; p += alignup((size_t)128 * 4);

  hipMemsetAsync(cnt, 0, (size_t)N * sizeof(int), stream);

  constexpr int VPT = 8;
  int egrid = (Etot + 256 * VPT - 1) / (256 * VPT);

  wprep_kernel<<<65, 256, 0, stream>>>(W1, W2, as2, ad2, lw, wp1, vsrc2, vdst2, vlin);
  hist_kernel<VPT><<<egrid, 256, 0, stream>>>(ei, E, N, cnt);
  bsum_kernel<<<B, 256, 0, stream>>>(cnt, bsum, N);
  scan196_kernel<<<1, 256, 0, stream>>>(bsum, bbase, B);
  offs_kernel<<<B, 256, 0, stream>>>(cnt, bbase, off, cur, N, Etot);
  scatter_kernel<VPT><<<egrid, 256, 0, stream>>>(ei, E, N, cur, eps);

  gemm1_kernel<<<(N + 31) / 32, 256, 0, stream>>>(
      x, (const uint4*)wp1, as1, ad1, h1b, als, ald, N);
  agg1_kernel<<<(N + 3) / 4, 256, 0, stream>>>(h1b, als, ald, eps, off, b1,
                                               vsrc2, vdst2, vlin, gsrc, adst2, N);
  agg2_kernel<<<(N + 3) / 4, 256, 0, stream>>>(gsrc, adst2, eps, off, b2, lw, lb, out, N);
}

// Round 12
// 150.280 us; speedup vs baseline: 1.9688x; 1.9688x over previous
//
#include <hip/hip_runtime.h>
#include <hip/hip_fp16.h>

// GAT regression: 2-layer GAT + linear head.
// R19: CSR build REVERTED to the bucketed 2-level sort (R17) — R18's flat
//      scatter caused 35x write amplification (random u16 stores from all 8
//      XCDs bounce non-coherent L2 lines; 114MB written for 3.3MB payload,
//      150us). Bucketed csr_build writes stay block-local -> full-line
//      assembly in one XCD's L2. Kept from R18: u16 eps (src-only) output,
//      halving the CSR write and the agg-side epair stream.
// R17 retained: gemm2 deleted (projection vectors in agg1 epilogue), MFMA
//      gemm1 with LDS-staged A, fp8 e4m3 H1 rows, in-agg softmax weights,
//      scalar agg2 on the (logit,s) table.
// Requires N < 65536 (16-bit packing). N = 50000.

#define LEAKY(x) ((x) > 0.f ? (x) : 0.2f * (x))

typedef float v2f __attribute__((ext_vector_type(2)));
typedef _Float16 f16x8 __attribute__((ext_vector_type(8)));
typedef __fp16 h16x2 __attribute__((ext_vector_type(2)));
typedef float f32x4 __attribute__((ext_vector_type(4)));

// ---------------- bucketed CSR build (R17 structure, u16 output) ------------

template <int VPT>
__global__ __launch_bounds__(256) void bucket_cnt_kernel(const int* __restrict__ ei, int E, int n,
                                                         int* __restrict__ bc) {
  __shared__ int lc[256];
  int t = threadIdx.x;
  lc[t] = 0;
  __syncthreads();
  int base = blockIdx.x * (256 * VPT) + t;
  int tot = E + n;
#pragma unroll
  for (int u = 0; u < VPT; ++u) {
    int i = base + u * 256;
    if (i < tot) {
      int d = (i < E) ? ei[E + i] : (i - E);
      atomicAdd(&lc[d >> 8], 1);
    }
  }
  __syncthreads();
  if (lc[t]) atomicAdd(&bc[t], lc[t]);
}

__global__ __launch_bounds__(256) void bucket_scan_kernel(const int* __restrict__ bc,
                                                          int* __restrict__ boff,
                                                          int* __restrict__ bcur, int B,
                                                          int* __restrict__ off, int n, int Etot) {
  __shared__ int sm[256];
  int t = threadIdx.x;
  int v = (t < B) ? bc[t] : 0;
  sm[t] = v;
  __syncthreads();
  for (int s = 1; s < 256; s <<= 1) {
    int a = (t >= s) ? sm[t - s] : 0;
    __syncthreads();
    sm[t] += a;
    __syncthreads();
  }
  int excl = sm[t] - v;
  if (t < B) { boff[t] = excl; bcur[t] = excl; }
  if (t == 0) { boff[B] = Etot; off[n] = Etot; }
}

template <int VPT>
__global__ __launch_bounds__(256) void bucket_scatter_kernel(const int* __restrict__ ei, int E,
                                                             int n, int* __restrict__ bcur,
                                                             unsigned* __restrict__ entries) {
  __shared__ int lc[256];
  __shared__ int lbase[256];
  int t = threadIdx.x;
  lc[t] = 0;
  __syncthreads();
  int base = blockIdx.x * (256 * VPT) + t;
  int tot = E + n;
  int bb[VPT], ll[VPT];
  unsigned pk[VPT];
#pragma unroll
  for (int u = 0; u < VPT; ++u) {
    int i = base + u * 256;
    bb[u] = -1;
    if (i < tot) {
      int s, d;
      if (i < E) { s = ei[i]; d = ei[E + i]; }
      else       { s = d = i - E; }
      int b = d >> 8;
      bb[u] = b;
      ll[u] = atomicAdd(&lc[b], 1);
      pk[u] = (unsigned)s | ((unsigned)(d & 255) << 16);
    }
  }
  __syncthreads();
  if (lc[t]) lbase[t] = atomicAdd(&bcur[t], lc[t]);
  __syncthreads();
#pragma unroll
  for (int u = 0; u < VPT; ++u)
    if (bb[u] >= 0) entries[lbase[bb[u]] + ll[u]] = pk[u];
}

__global__ __launch_bounds__(256) void csr_build_kernel(const unsigned* __restrict__ entries,
                                                        const int* __restrict__ boff,
                                                        int* __restrict__ off,
                                                        unsigned short* __restrict__ eps, int n) {
  __shared__ int hist[256];
  __shared__ int scn[256];
  __shared__ int cur[256];
  int b = blockIdx.x, t = threadIdx.x;
  int k0 = boff[b], k1 = boff[b + 1];
  hist[t] = 0;
  __syncthreads();
  for (int k = k0 + t; k < k1; k += 256) atomicAdd(&hist[(entries[k] >> 16) & 255], 1);
  __syncthreads();
  int v = hist[t];
  scn[t] = v;
  __syncthreads();
  for (int s = 1; s < 256; s <<= 1) {
    int a = (t >= s) ? scn[t - s] : 0;
    __syncthreads();
    scn[t] += a;
    __syncthreads();
  }
  int excl = scn[t] - v;
  int d = (b << 8) + t;
  if (d < n) off[d] = k0 + excl;
  cur[t] = k0 + excl;
  __syncthreads();
  for (int k = k0 + t; k < k1; k += 256) {
    unsigned e = entries[k];
    unsigned dl = (e >> 16) & 255;
    int p = atomicAdd(&cur[dl], 1);
    eps[p] = (unsigned short)(e & 0xffffu);
  }
}

// ---------------- W prep: W1 fragment pack + layer-2 projection vectors -----

// W1 pack: element e = (((cn*4+kk)*4+g)*16+c)*8+i  stores W1[kk*32+g*8+i][cn*16+c]
// v-vectors: v_src2[k]=W2[k,:]·a_src2, v_dst2[k]=W2[k,:]·a_dst2, v_lin[k]=W2[k,:]·lin_w
__global__ __launch_bounds__(256) void wprep_kernel(const float* __restrict__ W1,
                                                    const float* __restrict__ W2,
                                                    const float* __restrict__ as2,
                                                    const float* __restrict__ ad2,
                                                    const float* __restrict__ lw,
                                                    unsigned short* __restrict__ Wp1,
                                                    float* __restrict__ vsrc2,
                                                    float* __restrict__ vdst2,
                                                    float* __restrict__ vlin) {
  int t = blockIdx.x * 256 + threadIdx.x;
  if (t < 16384) {
    int e = t;
    int i = e & 7;
    int c = (e >> 3) & 15;
    int g = (e >> 7) & 3;
    int kk = (e >> 9) & 3;
    int cn = e >> 11;
    int k = kk * 32 + g * 8 + i;
    int col = cn * 16 + c;
    __half h = __float2half(W1[k * 128 + col]);
    Wp1[e] = *(unsigned short*)&h;
  } else if (t < 16384 + 128) {
    int k = t - 16384;
    float a = 0.f, b = 0.f, s = 0.f;
    for (int cc = 0; cc < 64; ++cc) {
      float w = W2[k * 64 + cc];
      a = fmaf(w, as2[cc], a);
      b = fmaf(w, ad2[cc], b);
      s = fmaf(w, lw[cc], s);
    }
    vsrc2[k] = a;
    vdst2[k] = b;
    vlin[k] = s;
  }
}

// ---------------- MFMA GEMM1 + logits (LDS-staged A) ----------------

// block = 4 waves = 2M x 2N(head); 32 rows, N=128, H out fp8 e4m3.
__global__ __launch_bounds__(256) void gemm1_kernel(const float* __restrict__ X,
                                                    const uint4* __restrict__ Wp,
                                                    const float* __restrict__ a_src,
                                                    const float* __restrict__ a_dst,
                                                    unsigned char* __restrict__ Hout,
                                                    float2* __restrict__ als,
                                                    float2* __restrict__ ald, int n) {
  __shared__ float Xl[32 * 132];      // 32 rows x 128 f32, +4 pad (bank-friendly)
  __shared__ float lgt[2][2][2][16];  // [wm][head][src/dst][row]
  int t = threadIdx.x;
  int wave = t >> 6, lane = t & 63;
  int wm = wave >> 1, wn = wave & 1;
  int g = lane >> 4, c = lane & 15;
  int nb0 = blockIdx.x * 32;

  // ---- stage 32 rows coalesced (float4), padded rows of 132 floats ----
  {
    const float4* Xg = (const float4*)X;
    float4* Xs = (float4*)Xl;
#pragma unroll
    for (int u = 0; u < 4; ++u) {
      int idx = u * 256 + t;          // 0..1023 float4 slots
      int r = idx >> 5, c4 = idx & 31;
      int row = nb0 + r;
      int rc = row < n ? row : (n - 1);
      Xs[r * 33 + c4] = Xg[(size_t)rc * 32 + c4];
    }
  }
  __syncthreads();

  // ---- A fragments from LDS: row = wm*16+c, k = g*8 + i (+32*kk) ----
  f16x8 af[4];
  const float* xr = Xl + (wm * 16 + c) * 132 + g * 8;
#pragma unroll
  for (int kk = 0; kk < 4; ++kk) {
    float4 x0 = *(const float4*)(xr + kk * 32);
    float4 x1 = *(const float4*)(xr + kk * 32 + 4);
    union { f16x8 v; h16x2 p[4]; } A;
    A.p[0] = __builtin_amdgcn_cvt_pkrtz(x0.x, x0.y);
    A.p[1] = __builtin_amdgcn_cvt_pkrtz(x0.z, x0.w);
    A.p[2] = __builtin_amdgcn_cvt_pkrtz(x1.x, x1.y);
    A.p[3] = __builtin_amdgcn_cvt_pkrtz(x1.z, x1.w);
    af[kk] = A.v;
  }

  // ---- MFMA: 4 col-tiles x 4 k-steps ----
  f32x4 acc[4];
  f32x4 z = {0.f, 0.f, 0.f, 0.f};
#pragma unroll
  for (int cn = 0; cn < 4; ++cn) acc[cn] = z;
#pragma unroll
  for (int cn = 0; cn < 4; ++cn) {
    int cng = wn * 4 + cn;
#pragma unroll
    for (int kk = 0; kk < 4; ++kk) {
      union { uint4 u; f16x8 v; } B;
      B.u = Wp[(cng * 4 + kk) * 64 + lane];
      acc[cn] = __builtin_amdgcn_mfma_f32_16x16x32_f16(af[kk], B.v, acc[cn], 0, 0, 0);
    }
  }

  // ---- epilogue: fp8 H store + logit dots ----
  float asv[4], adv[4];
#pragma unroll
  for (int cn = 0; cn < 4; ++cn) {
    int col_l = wn * 64 + cn * 16 + c;
    asv[cn] = a_src[col_l];
    adv[cn] = a_dst[col_l];
  }
  float ps[4] = {0.f, 0.f, 0.f, 0.f};
  float pd[4] = {0.f, 0.f, 0.f, 0.f};
#pragma unroll
  for (int cn = 0; cn < 4; ++cn) {
#pragma unroll
    for (int r = 0; r < 4; ++r) {
      float v = acc[cn][r];
      ps[r] = fmaf(v, asv[cn], ps[r]);
      pd[r] = fmaf(v, adv[cn], pd[r]);
      int noder = nb0 + wm * 16 + g * 4 + r;
      int colg = wn * 64 + cn * 16 + c;
      if (noder < n) {
        int b8 = __builtin_amdgcn_cvt_pk_fp8_f32(v, v, 0, false);
        Hout[(size_t)noder * 128 + colg] = (unsigned char)(b8 & 0xff);
      }
    }
  }
#pragma unroll
  for (int r = 0; r < 4; ++r) {
#pragma unroll
    for (int m = 1; m <= 8; m <<= 1) {
      ps[r] += __shfl_xor(ps[r], m, 64);
      pd[r] += __shfl_xor(pd[r], m, 64);
    }
  }
  if (c == 0) {
#pragma unroll
    for (int r = 0; r < 4; ++r) {
      lgt[wm][wn][0][g * 4 + r] = ps[r];
      lgt[wm][wn][1][g * 4 + r] = pd[r];
    }
  }
  __syncthreads();
  if (t < 32) {
    int wmm = t >> 4, row = t & 15;
    int node = nb0 + wmm * 16 + row;
    if (node < n) {
      als[node] = make_float2(lgt[wmm][0][0][row], lgt[wmm][1][0][row]);
      ald[node] = make_float2(lgt[wmm][0][1][row], lgt[wmm][1][1][row]);
    }
  }
}

// ---------------- aggregation ----------------

// layer 1 (fp8 rows, 128B) + fused layer-2 projection epilogue.
__global__ __launch_bounds__(256) void agg1_kernel(const unsigned char* __restrict__ Hb8,
                                                   const float2* __restrict__ als,
                                                   const float2* __restrict__ ald,
                                                   const unsigned short* __restrict__ eps,
                                                   const int* __restrict__ off,
                                                   const float* __restrict__ b1,
                                                   const float* __restrict__ vsrc2,
                                                   const float* __restrict__ vdst2,
                                                   const float* __restrict__ vlin,
                                                   float2* __restrict__ gsrc,
                                                   float* __restrict__ adst2, int n) {
  __shared__ float wlds[4][128];
  int wid = (blockIdx.x * 256 + threadIdx.x) >> 6;
  int lane = threadIdx.x & 63;
  if (wid >= n) return;
  wid = __builtin_amdgcn_readfirstlane(wid);
  int wslot = (threadIdx.x >> 6) & 3;
  int half = lane >> 5;
  int k0 = off[wid], k1 = off[wid + 1];
  const unsigned short* Hu = (const unsigned short*)Hb8;
  float2 advv = ald[wid];
  float* wrow = &wlds[wslot][half << 6];

  float ax = 0.f, ay = 0.f, den = 0.f;

  for (int kb = k0; kb < k1; kb += 64) {
    int rem = min(k1 - kb, 64);
    int e = kb + (lane < rem ? lane : rem - 1);
    unsigned pp = eps[e];
    float2 l = als[pp];
    float g0 = __expf(LEAKY(l.x + advv.x));
    float g1 = __expf(LEAKY(l.y + advv.y));
    wlds[wslot][lane] = g0;
    wlds[wslot][64 + lane] = g1;

#define EDGE1(jj)                                                                   \
  {                                                                                 \
    unsigned p = (unsigned)__builtin_amdgcn_readlane((int)pp, (jj));                \
    float w = wrow[(jj)];                                                           \
    unsigned short hv = Hu[(p << 6) | (unsigned)lane];                              \
    v2f hf = __builtin_amdgcn_cvt_pk_f32_fp8((int)hv, false);                       \
    den += w;                                                                       \
    ax = fmaf(hf.x, w, ax);                                                         \
    ay = fmaf(hf.y, w, ay);                                                         \
  }

    int nb = rem >> 3;
    for (int b = 0; b < nb; ++b) {
      int jb = b << 3;
#pragma unroll
      for (int j = 0; j < 8; ++j) EDGE1(jb + j);
    }
    for (int jj = nb << 3; jj < rem; ++jj) EDGE1(jj);
#undef EDGE1
  }

  // elu(out + b1), then project onto the three layer-2 vectors.
  float inv = 1.f / (den + 1e-16f);
  float2 bv = ((const float2*)b1)[lane];
  float r0 = ax * inv + bv.x;
  float r1 = ay * inv + bv.y;
  r0 = r0 > 0.f ? r0 : (__expf(r0) - 1.f);
  r1 = r1 > 0.f ? r1 : (__expf(r1) - 1.f);
  float2 vs = ((const float2*)vsrc2)[lane];
  float2 vd = ((const float2*)vdst2)[lane];
  float2 vl = ((const float2*)vlin)[lane];
  float ps = r0 * vs.x + r1 * vs.y;
  float pd = r0 * vd.x + r1 * vd.y;
  float sv = r0 * vl.x + r1 * vl.y;
#pragma unroll
  for (int m = 1; m <= 32; m <<= 1) {
    ps += __shfl_xor(ps, m, 64);
    pd += __shfl_xor(pd, m, 64);
    sv += __shfl_xor(sv, m, 64);
  }
  if (lane == 0) {
    gsrc[wid] = make_float2(ps, sv);
    adst2[wid] = pd;
  }
}

// layer 2 + head, collapsed: per edge gather (logit_src, s) float2; scalar agg.
__global__ __launch_bounds__(256) void agg2_kernel(const float2* __restrict__ gsrc,
                                                   const float* __restrict__ adst2,
                                                   const unsigned short* __restrict__ eps,
                                                   const int* __restrict__ off,
                                                   const float* __restrict__ b2,
                                                   const float* __restrict__ lin_w,
                                                   const float* __restrict__ lin_b,
                                                   float* __restrict__ out, int n) {
  int wid = (blockIdx.x * 256 + threadIdx.x) >> 6;
  int lane = threadIdx.x & 63;
  if (wid >= n) return;
  wid = __builtin_amdgcn_readfirstlane(wid);
  int k0 = off[wid], k1 = off[wid + 1];
  float adv = adst2[wid];

  float num = 0.f, den = 0.f;
  for (int kb = k0; kb < k1; kb += 64) {
    int e = kb + lane;
    bool ok = e < k1;
    unsigned pp = eps[ok ? e : k0];
    float2 g = gsrc[pp];
    float w = ok ? __expf(LEAKY(g.x + adv)) : 0.f;
    num = fmaf(w, g.y, num);
    den += w;
  }
  float bt = b2[lane] * lin_w[lane];  // lanes cover all 64 ch -> b2.lin_w
#pragma unroll
  for (int m = 1; m <= 32; m <<= 1) {
    num += __shfl_xor(num, m, 64);
    den += __shfl_xor(den, m, 64);
    bt  += __shfl_xor(bt, m, 64);
  }
  if (lane == 0) out[wid] = num / (den + 1e-16f) + bt + lin_b[0];
}

// ---------------- launcher ----------------

static inline size_t alignup(size_t v) { return (v + 255) & ~(size_t)255; }

extern "C" void kernel_launch(void* const* d_in, const int* in_sizes, int n_in,
                              void* d_out, int out_size, void* d_ws, size_t ws_size,
                              hipStream_t stream) {
  const float* x   = (const float*)d_in[0];
  const int*   ei  = (const int*)d_in[1];
  const float* W1  = (const float*)d_in[2];
  const float* as1 = (const float*)d_in[3];
  const float* ad1 = (const float*)d_in[4];
  const float* b1  = (const float*)d_in[5];
  const float* W2  = (const float*)d_in[6];
  const float* as2 = (const float*)d_in[7];
  const float* ad2 = (const float*)d_in[8];
  const float* b2  = (const float*)d_in[9];
  const float* lw  = (const float*)d_in[10];
  const float* lb  = (const float*)d_in[11];
  float* out = (float*)d_out;

  const int N = out_size;          // 50000
  const int E = in_sizes[1] / 2;   // 1600000
  const int Etot = E + N;
  const int B = (N + 255) >> 8;    // 196 buckets

  char* p = (char*)d_ws;
  int* bcnt = (int*)p;  p += alignup((size_t)(B + 1) * 4);
  int* boff = (int*)p;  p += alignup((size_t)(B + 1) * 4);
  int* bcur = (int*)p;  p += alignup((size_t)B * 4);
  unsigned* entries = (unsigned*)p; p += alignup((size_t)Etot * 4);
  int* off  = (int*)p;  p += alignup((size_t)(N + 1) * 4);
  unsigned short* eps = (unsigned short*)p; p += alignup((size_t)Etot * 2);
  float2* als = (float2*)p; p += alignup((size_t)N * 8);
  float2* ald = (float2*)p; p += alignup((size_t)N * 8);
  float2* gsrc = (float2*)p; p += alignup((size_t)N * 8);
  float* adst2 = (float*)p; p += alignup((size_t)N * 4);
  unsigned char* h1b = (unsigned char*)p; p += alignup((size_t)N * 128);
  unsigned short* wp1 = (unsigned short*)p; p += alignup((size_t)16384 * 2);
  float* vsrc2 = (float*)p; p += alignup((size_t)128 * 4);
  float* vdst2 = (float*)p; p += alignup((size_t)128 * 4);
  float* vlin  = (float*)p; p += alignup((size_t)128 * 4);

  hipMemsetAsync(bcnt, 0, (size_t)(B + 1) * sizeof(int), stream);

  constexpr int VPT = 8;
  int egrid = (Etot + 256 * VPT - 1) / (256 * VPT);

  wprep_kernel<<<65, 256, 0, stream>>>(W1, W2, as2, ad2, lw, wp1, vsrc2, vdst2, vlin);
  bucket_cnt_kernel<VPT><<<egrid, 256, 0, stream>>>(ei, E, N, bcnt);
  bucket_scan_kernel<<<1, 256, 0, stream>>>(bcnt, boff, bcur, B, off, N, Etot);
  bucket_scatter_kernel<VPT><<<egrid, 256, 0, stream>>>(ei, E, N, bcur, entries);
  csr_build_kernel<<<B, 256, 0, stream>>>(entries, boff, off, eps, N);

  gemm1_kernel<<<(N + 31) / 32, 256, 0, stream>>>(
      x, (const uint4*)wp1, as1, ad1, h1b, als, ald, N);
  agg1_kernel<<<(N + 3) / 4, 256, 0, stream>>>(h1b, als, ald, eps, off, b1,
                                               vsrc2, vdst2, vlin, gsrc, adst2, N);
  agg2_kernel<<<(N + 3) / 4, 256, 0, stream>>>(gsrc, adst2, eps, off, b2, lw, lb, out, N);
}

// Round 13
// 149.042 us; speedup vs baseline: 1.9852x; 1.0083x over previous
//
#include <hip/hip_runtime.h>
#include <hip/hip_fp16.h>

// GAT regression: 2-layer GAT + linear head.
// R20: (1) hipMemsetAsync(bcnt) DELETED — the rocclr fill blit for 788B cost
//      ~45us per iteration (profiled 45.8us at 0.18GB/s); bcnt is now zeroed
//      by block 0 of wprep_kernel (runs before bucket_cnt in-stream).
//      (2) agg1: den moved out of the FMA loop — computed per 64-edge
//      superchunk in the weight phase via one masked 64-lane butterfly
//      (12 shfl vs 64 per-edge adds); head-select at the end.
// R19 retained: bucketed CSR (u16 eps), gemm2 deleted (projection vectors in
//      agg1 epilogue), MFMA gemm1 with LDS-staged A, fp8 e4m3 H1 rows,
//      in-agg softmax weights, scalar agg2 on the (logit,s) table.
// Requires N < 65536 (16-bit packing). N = 50000.

#define LEAKY(x) ((x) > 0.f ? (x) : 0.2f * (x))

typedef float v2f __attribute__((ext_vector_type(2)));
typedef _Float16 f16x8 __attribute__((ext_vector_type(8)));
typedef __fp16 h16x2 __attribute__((ext_vector_type(2)));
typedef float f32x4 __attribute__((ext_vector_type(4)));

// ---------------- bucketed CSR build (u16 output) ------------

template <int VPT>
__global__ __launch_bounds__(256) void bucket_cnt_kernel(const int* __restrict__ ei, int E, int n,
                                                         int* __restrict__ bc) {
  __shared__ int lc[256];
  int t = threadIdx.x;
  lc[t] = 0;
  __syncthreads();
  int base = blockIdx.x * (256 * VPT) + t;
  int tot = E + n;
#pragma unroll
  for (int u = 0; u < VPT; ++u) {
    int i = base + u * 256;
    if (i < tot) {
      int d = (i < E) ? ei[E + i] : (i - E);
      atomicAdd(&lc[d >> 8], 1);
    }
  }
  __syncthreads();
  if (lc[t]) atomicAdd(&bc[t], lc[t]);
}

__global__ __launch_bounds__(256) void bucket_scan_kernel(const int* __restrict__ bc,
                                                          int* __restrict__ boff,
                                                          int* __restrict__ bcur, int B,
                                                          int* __restrict__ off, int n, int Etot) {
  __shared__ int sm[256];
  int t = threadIdx.x;
  int v = (t < B) ? bc[t] : 0;
  sm[t] = v;
  __syncthreads();
  for (int s = 1; s < 256; s <<= 1) {
    int a = (t >= s) ? sm[t - s] : 0;
    __syncthreads();
    sm[t] += a;
    __syncthreads();
  }
  int excl = sm[t] - v;
  if (t < B) { boff[t] = excl; bcur[t] = excl; }
  if (t == 0) { boff[B] = Etot; off[n] = Etot; }
}

template <int VPT>
__global__ __launch_bounds__(256) void bucket_scatter_kernel(const int* __restrict__ ei, int E,
                                                             int n, int* __restrict__ bcur,
                                                             unsigned* __restrict__ entries) {
  __shared__ int lc[256];
  __shared__ int lbase[256];
  int t = threadIdx.x;
  lc[t] = 0;
  __syncthreads();
  int base = blockIdx.x * (256 * VPT) + t;
  int tot = E + n;
  int bb[VPT], ll[VPT];
  unsigned pk[VPT];
#pragma unroll
  for (int u = 0; u < VPT; ++u) {
    int i = base + u * 256;
    bb[u] = -1;
    if (i < tot) {
      int s, d;
      if (i < E) { s = ei[i]; d = ei[E + i]; }
      else       { s = d = i - E; }
      int b = d >> 8;
      bb[u] = b;
      ll[u] = atomicAdd(&lc[b], 1);
      pk[u] = (unsigned)s | ((unsigned)(d & 255) << 16);
    }
  }
  __syncthreads();
  if (lc[t]) lbase[t] = atomicAdd(&bcur[t], lc[t]);
  __syncthreads();
#pragma unroll
  for (int u = 0; u < VPT; ++u)
    if (bb[u] >= 0) entries[lbase[bb[u]] + ll[u]] = pk[u];
}

__global__ __launch_bounds__(256) void csr_build_kernel(const unsigned* __restrict__ entries,
                                                        const int* __restrict__ boff,
                                                        int* __restrict__ off,
                                                        unsigned short* __restrict__ eps, int n) {
  __shared__ int hist[256];
  __shared__ int scn[256];
  __shared__ int cur[256];
  int b = blockIdx.x, t = threadIdx.x;
  int k0 = boff[b], k1 = boff[b + 1];
  hist[t] = 0;
  __syncthreads();
  for (int k = k0 + t; k < k1; k += 256) atomicAdd(&hist[(entries[k] >> 16) & 255], 1);
  __syncthreads();
  int v = hist[t];
  scn[t] = v;
  __syncthreads();
  for (int s = 1; s < 256; s <<= 1) {
    int a = (t >= s) ? scn[t - s] : 0;
    __syncthreads();
    scn[t] += a;
    __syncthreads();
  }
  int excl = scn[t] - v;
  int d = (b << 8) + t;
  if (d < n) off[d] = k0 + excl;
  cur[t] = k0 + excl;
  __syncthreads();
  for (int k = k0 + t; k < k1; k += 256) {
    unsigned e = entries[k];
    unsigned dl = (e >> 16) & 255;
    int p = atomicAdd(&cur[dl], 1);
    eps[p] = (unsigned short)(e & 0xffffu);
  }
}

// ---------------- W prep: bcnt zero + W1 pack + layer-2 projection vectors --

__global__ __launch_bounds__(256) void wprep_kernel(const float* __restrict__ W1,
                                                    const float* __restrict__ W2,
                                                    const float* __restrict__ as2,
                                                    const float* __restrict__ ad2,
                                                    const float* __restrict__ lw,
                                                    unsigned short* __restrict__ Wp1,
                                                    float* __restrict__ vsrc2,
                                                    float* __restrict__ vdst2,
                                                    float* __restrict__ vlin,
                                                    int* __restrict__ bcnt, int B) {
  if (blockIdx.x == 0 && threadIdx.x <= (unsigned)B) bcnt[threadIdx.x] = 0;
  int t = blockIdx.x * 256 + threadIdx.x;
  if (t < 16384) {
    int e = t;
    int i = e & 7;
    int c = (e >> 3) & 15;
    int g = (e >> 7) & 3;
    int kk = (e >> 9) & 3;
    int cn = e >> 11;
    int k = kk * 32 + g * 8 + i;
    int col = cn * 16 + c;
    __half h = __float2half(W1[k * 128 + col]);
    Wp1[e] = *(unsigned short*)&h;
  } else if (t < 16384 + 128) {
    int k = t - 16384;
    float a = 0.f, b = 0.f, s = 0.f;
    for (int cc = 0; cc < 64; ++cc) {
      float w = W2[k * 64 + cc];
      a = fmaf(w, as2[cc], a);
      b = fmaf(w, ad2[cc], b);
      s = fmaf(w, lw[cc], s);
    }
    vsrc2[k] = a;
    vdst2[k] = b;
    vlin[k] = s;
  }
}

// ---------------- MFMA GEMM1 + logits (LDS-staged A) ----------------

// block = 4 waves = 2M x 2N(head); 32 rows, N=128, H out fp8 e4m3.
__global__ __launch_bounds__(256) void gemm1_kernel(const float* __restrict__ X,
                                                    const uint4* __restrict__ Wp,
                                                    const float* __restrict__ a_src,
                                                    const float* __restrict__ a_dst,
                                                    unsigned char* __restrict__ Hout,
                                                    float2* __restrict__ als,
                                                    float2* __restrict__ ald, int n) {
  __shared__ float Xl[32 * 132];      // 32 rows x 128 f32, +4 pad (bank-friendly)
  __shared__ float lgt[2][2][2][16];  // [wm][head][src/dst][row]
  int t = threadIdx.x;
  int wave = t >> 6, lane = t & 63;
  int wm = wave >> 1, wn = wave & 1;
  int g = lane >> 4, c = lane & 15;
  int nb0 = blockIdx.x * 32;

  // ---- stage 32 rows coalesced (float4), padded rows of 132 floats ----
  {
    const float4* Xg = (const float4*)X;
    float4* Xs = (float4*)Xl;
#pragma unroll
    for (int u = 0; u < 4; ++u) {
      int idx = u * 256 + t;          // 0..1023 float4 slots
      int r = idx >> 5, c4 = idx & 31;
      int row = nb0 + r;
      int rc = row < n ? row : (n - 1);
      Xs[r * 33 + c4] = Xg[(size_t)rc * 32 + c4];
    }
  }
  __syncthreads();

  // ---- A fragments from LDS: row = wm*16+c, k = g*8 + i (+32*kk) ----
  f16x8 af[4];
  const float* xr = Xl + (wm * 16 + c) * 132 + g * 8;
#pragma unroll
  for (int kk = 0; kk < 4; ++kk) {
    float4 x0 = *(const float4*)(xr + kk * 32);
    float4 x1 = *(const float4*)(xr + kk * 32 + 4);
    union { f16x8 v; h16x2 p[4]; } A;
    A.p[0] = __builtin_amdgcn_cvt_pkrtz(x0.x, x0.y);
    A.p[1] = __builtin_amdgcn_cvt_pkrtz(x0.z, x0.w);
    A.p[2] = __builtin_amdgcn_cvt_pkrtz(x1.x, x1.y);
    A.p[3] = __builtin_amdgcn_cvt_pkrtz(x1.z, x1.w);
    af[kk] = A.v;
  }

  // ---- MFMA: 4 col-tiles x 4 k-steps ----
  f32x4 acc[4];
  f32x4 z = {0.f, 0.f, 0.f, 0.f};
#pragma unroll
  for (int cn = 0; cn < 4; ++cn) acc[cn] = z;
#pragma unroll
  for (int cn = 0; cn < 4; ++cn) {
    int cng = wn * 4 + cn;
#pragma unroll
    for (int kk = 0; kk < 4; ++kk) {
      union { uint4 u; f16x8 v; } B;
      B.u = Wp[(cng * 4 + kk) * 64 + lane];
      acc[cn] = __builtin_amdgcn_mfma_f32_16x16x32_f16(af[kk], B.v, acc[cn], 0, 0, 0);
    }
  }

  // ---- epilogue: fp8 H store + logit dots ----
  float asv[4], adv[4];
#pragma unroll
  for (int cn = 0; cn < 4; ++cn) {
    int col_l = wn * 64 + cn * 16 + c;
    asv[cn] = a_src[col_l];
    adv[cn] = a_dst[col_l];
  }
  float ps[4] = {0.f, 0.f, 0.f, 0.f};
  float pd[4] = {0.f, 0.f, 0.f, 0.f};
#pragma unroll
  for (int cn = 0; cn < 4; ++cn) {
#pragma unroll
    for (int r = 0; r < 4; ++r) {
      float v = acc[cn][r];
      ps[r] = fmaf(v, asv[cn], ps[r]);
      pd[r] = fmaf(v, adv[cn], pd[r]);
      int noder = nb0 + wm * 16 + g * 4 + r;
      int colg = wn * 64 + cn * 16 + c;
      if (noder < n) {
        int b8 = __builtin_amdgcn_cvt_pk_fp8_f32(v, v, 0, false);
        Hout[(size_t)noder * 128 + colg] = (unsigned char)(b8 & 0xff);
      }
    }
  }
#pragma unroll
  for (int r = 0; r < 4; ++r) {
#pragma unroll
    for (int m = 1; m <= 8; m <<= 1) {
      ps[r] += __shfl_xor(ps[r], m, 64);
      pd[r] += __shfl_xor(pd[r], m, 64);
    }
  }
  if (c == 0) {
#pragma unroll
    for (int r = 0; r < 4; ++r) {
      lgt[wm][wn][0][g * 4 + r] = ps[r];
      lgt[wm][wn][1][g * 4 + r] = pd[r];
    }
  }
  __syncthreads();
  if (t < 32) {
    int wmm = t >> 4, row = t & 15;
    int node = nb0 + wmm * 16 + row;
    if (node < n) {
      als[node] = make_float2(lgt[wmm][0][0][row], lgt[wmm][1][0][row]);
      ald[node] = make_float2(lgt[wmm][0][1][row], lgt[wmm][1][1][row]);
    }
  }
}

// ---------------- aggregation ----------------

// layer 1 (fp8 rows, 128B) + fused layer-2 projection epilogue.
// den computed in weight phase (masked 64-lane butterfly per superchunk).
__global__ __launch_bounds__(256) void agg1_kernel(const unsigned char* __restrict__ Hb8,
                                                   const float2* __restrict__ als,
                                                   const float2* __restrict__ ald,
                                                   const unsigned short* __restrict__ eps,
                                                   const int* __restrict__ off,
                                                   const float* __restrict__ b1,
                                                   const float* __restrict__ vsrc2,
                                                   const float* __restrict__ vdst2,
                                                   const float* __restrict__ vlin,
                                                   float2* __restrict__ gsrc,
                                                   float* __restrict__ adst2, int n) {
  __shared__ float wlds[4][128];
  int wid = (blockIdx.x * 256 + threadIdx.x) >> 6;
  int lane = threadIdx.x & 63;
  if (wid >= n) return;
  wid = __builtin_amdgcn_readfirstlane(wid);
  int wslot = (threadIdx.x >> 6) & 3;
  int half = lane >> 5;
  int k0 = off[wid], k1 = off[wid + 1];
  const unsigned short* Hu = (const unsigned short*)Hb8;
  float2 advv = ald[wid];
  float* wrow = &wlds[wslot][half << 6];

  float ax = 0.f, ay = 0.f, den0 = 0.f, den1 = 0.f;

  for (int kb = k0; kb < k1; kb += 64) {
    int rem = min(k1 - kb, 64);
    int e = kb + (lane < rem ? lane : rem - 1);
    unsigned pp = eps[e];
    float2 l = als[pp];
    float g0 = __expf(LEAKY(l.x + advv.x));
    float g1 = __expf(LEAKY(l.y + advv.y));
    wlds[wslot][lane] = g0;
    wlds[wslot][64 + lane] = g1;
    // den: masked butterfly (duplicated-lane weights zeroed)
    float g0m = (lane < rem) ? g0 : 0.f;
    float g1m = (lane < rem) ? g1 : 0.f;
#pragma unroll
    for (int m = 1; m <= 32; m <<= 1) {
      g0m += __shfl_xor(g0m, m, 64);
      g1m += __shfl_xor(g1m, m, 64);
    }
    den0 += g0m;
    den1 += g1m;

#define EDGE1(jj)                                                                   \
  {                                                                                 \
    unsigned p = (unsigned)__builtin_amdgcn_readlane((int)pp, (jj));                \
    float w = wrow[(jj)];                                                           \
    unsigned short hv = Hu[(p << 6) | (unsigned)lane];                              \
    v2f hf = __builtin_amdgcn_cvt_pk_f32_fp8((int)hv, false);                       \
    ax = fmaf(hf.x, w, ax);                                                         \
    ay = fmaf(hf.y, w, ay);                                                         \
  }

    int nb = rem >> 3;
    for (int b = 0; b < nb; ++b) {
      int jb = b << 3;
#pragma unroll
      for (int j = 0; j < 8; ++j) EDGE1(jb + j);
    }
    for (int jj = nb << 3; jj < rem; ++jj) EDGE1(jj);
#undef EDGE1
  }

  // elu(out + b1), then project onto the three layer-2 vectors.
  float den = half ? den1 : den0;
  float inv = 1.f / (den + 1e-16f);
  float2 bv = ((const float2*)b1)[lane];
  float r0 = ax * inv + bv.x;
  float r1 = ay * inv + bv.y;
  r0 = r0 > 0.f ? r0 : (__expf(r0) - 1.f);
  r1 = r1 > 0.f ? r1 : (__expf(r1) - 1.f);
  float2 vs = ((const float2*)vsrc2)[lane];
  float2 vd = ((const float2*)vdst2)[lane];
  float2 vl = ((const float2*)vlin)[lane];
  float ps = r0 * vs.x + r1 * vs.y;
  float pd = r0 * vd.x + r1 * vd.y;
  float sv = r0 * vl.x + r1 * vl.y;
#pragma unroll
  for (int m = 1; m <= 32; m <<= 1) {
    ps += __shfl_xor(ps, m, 64);
    pd += __shfl_xor(pd, m, 64);
    sv += __shfl_xor(sv, m, 64);
  }
  if (lane == 0) {
    gsrc[wid] = make_float2(ps, sv);
    adst2[wid] = pd;
  }
}

// layer 2 + head, collapsed: per edge gather (logit_src, s) float2; scalar agg.
__global__ __launch_bounds__(256) void agg2_kernel(const float2* __restrict__ gsrc,
                                                   const float* __restrict__ adst2,
                                                   const unsigned short* __restrict__ eps,
                                                   const int* __restrict__ off,
                                                   const float* __restrict__ b2,
                                                   const float* __restrict__ lin_w,
                                                   const float* __restrict__ lin_b,
                                                   float* __restrict__ out, int n) {
  int wid = (blockIdx.x * 256 + threadIdx.x) >> 6;
  int lane = threadIdx.x & 63;
  if (wid >= n) return;
  wid = __builtin_amdgcn_readfirstlane(wid);
  int k0 = off[wid], k1 = off[wid + 1];
  float adv = adst2[wid];

  float num = 0.f, den = 0.f;
  for (int kb = k0; kb < k1; kb += 64) {
    int e = kb + lane;
    bool ok = e < k1;
    unsigned pp = eps[ok ? e : k0];
    float2 g = gsrc[pp];
    float w = ok ? __expf(LEAKY(g.x + adv)) : 0.f;
    num = fmaf(w, g.y, num);
    den += w;
  }
  float bt = b2[lane] * lin_w[lane];  // lanes cover all 64 ch -> b2.lin_w
#pragma unroll
  for (int m = 1; m <= 32; m <<= 1) {
    num += __shfl_xor(num, m, 64);
    den += __shfl_xor(den, m, 64);
    bt  += __shfl_xor(bt, m, 64);
  }
  if (lane == 0) out[wid] = num / (den + 1e-16f) + bt + lin_b[0];
}

// ---------------- launcher ----------------

static inline size_t alignup(size_t v) { return (v + 255) & ~(size_t)255; }

extern "C" void kernel_launch(void* const* d_in, const int* in_sizes, int n_in,
                              void* d_out, int out_size, void* d_ws, size_t ws_size,
                              hipStream_t stream) {
  const float* x   = (const float*)d_in[0];
  const int*   ei  = (const int*)d_in[1];
  const float* W1  = (const float*)d_in[2];
  const float* as1 = (const float*)d_in[3];
  const float* ad1 = (const float*)d_in[4];
  const float* b1  = (const float*)d_in[5];
  const float* W2  = (const float*)d_in[6];
  const float* as2 = (const float*)d_in[7];
  const float* ad2 = (const float*)d_in[8];
  const float* b2  = (const float*)d_in[9];
  const float* lw  = (const float*)d_in[10];
  const float* lb  = (const float*)d_in[11];
  float* out = (float*)d_out;

  const int N = out_size;          // 50000
  const int E = in_sizes[1] / 2;   // 1600000
  const int Etot = E + N;
  const int B = (N + 255) >> 8;    // 196 buckets

  char* p = (char*)d_ws;
  int* bcnt = (int*)p;  p += alignup((size_t)(B + 1) * 4);
  int* boff = (int*)p;  p += alignup((size_t)(B + 1) * 4);
  int* bcur = (int*)p;  p += alignup((size_t)B * 4);
  unsigned* entries = (unsigned*)p; p += alignup((size_t)Etot * 4);
  int* off  = (int*)p;  p += alignup((size_t)(N + 1) * 4);
  unsigned short* eps = (unsigned short*)p; p += alignup((size_t)Etot * 2);
  float2* als = (float2*)p; p += alignup((size_t)N * 8);
  float2* ald = (float2*)p; p += alignup((size_t)N * 8);
  float2* gsrc = (float2*)p; p += alignup((size_t)N * 8);
  float* adst2 = (float*)p; p += alignup((size_t)N * 4);
  unsigned char* h1b = (unsigned char*)p; p += alignup((size_t)N * 128);
  unsigned short* wp1 = (unsigned short*)p; p += alignup((size_t)16384 * 2);
  float* vsrc2 = (float*)p; p += alignup((size_t)128 * 4);
  float* vdst2 = (float*)p; p += alignup((size_t)128 * 4);
  float* vlin  = (float*)p; p += alignup((size_t)128 * 4);

  constexpr int VPT = 8;
  int egrid = (Etot + 256 * VPT - 1) / (256 * VPT);

  wprep_kernel<<<65, 256, 0, stream>>>(W1, W2, as2, ad2, lw, wp1, vsrc2, vdst2, vlin,
                                       bcnt, B);
  bucket_cnt_kernel<VPT><<<egrid, 256, 0, stream>>>(ei, E, N, bcnt);
  bucket_scan_kernel<<<1, 256, 0, stream>>>(bcnt, boff, bcur, B, off, N, Etot);
  bucket_scatter_kernel<VPT><<<egrid, 256, 0, stream>>>(ei, E, N, bcur, entries);
  csr_build_kernel<<<B, 256, 0, stream>>>(entries, boff, off, eps, N);

  gemm1_kernel<<<(N + 31) / 32, 256, 0, stream>>>(
      x, (const uint4*)wp1, as1, ad1, h1b, als, ald, N);
  agg1_kernel<<<(N + 3) / 4, 256, 0, stream>>>(h1b, als, ald, eps, off, b1,
                                               vsrc2, vdst2, vlin, gsrc, adst2, N);
  agg2_kernel<<<(N + 3) / 4, 256, 0, stream>>>(gsrc, adst2, eps, off, b2, lw, lb, out, N);
}

// Round 14
// 145.945 us; speedup vs baseline: 2.0273x; 1.0212x over previous
//
#include <hip/hip_runtime.h>
#include <hip/hip_fp16.h>

// GAT regression: 2-layer GAT + linear head.
// R21: (1) agg1 reverted to R19 inner loop (per-edge den add — R20's den
//      butterfly cost +2.4us and +12 VGPR). (2) bucket_scan kernel DELETED:
//      each bucket_scatter/csr_build block recomputes the 196-entry scan
//      locally (16-step LDS scan, ~negligible); scatter uses zero-based
//      relative cursors (bcur_rel, zeroed in wprep); off[n]=Etot in wprep.
//      Removes one dispatch + the 1-block whole-GPU serialization point.
// R19 retained: bucketed CSR (u16 eps), gemm2 deleted (projection vectors in
//      agg1 epilogue), MFMA gemm1 with LDS-staged A, fp8 e4m3 H1 rows,
//      in-agg softmax weights, scalar agg2 on the (logit,s) table.
// Requires N < 65536 (16-bit packing). N = 50000.

#define LEAKY(x) ((x) > 0.f ? (x) : 0.2f * (x))

typedef float v2f __attribute__((ext_vector_type(2)));
typedef _Float16 f16x8 __attribute__((ext_vector_type(8)));
typedef __fp16 h16x2 __attribute__((ext_vector_type(2)));
typedef float f32x4 __attribute__((ext_vector_type(4)));

// ---------------- bucketed CSR build (u16 output, local scans) --------------

template <int VPT>
__global__ __launch_bounds__(256) void bucket_cnt_kernel(const int* __restrict__ ei, int E, int n,
                                                         int* __restrict__ bc) {
  __shared__ int lc[256];
  int t = threadIdx.x;
  lc[t] = 0;
  __syncthreads();
  int base = blockIdx.x * (256 * VPT) + t;
  int tot = E + n;
#pragma unroll
  for (int u = 0; u < VPT; ++u) {
    int i = base + u * 256;
    if (i < tot) {
      int d = (i < E) ? ei[E + i] : (i - E);
      atomicAdd(&lc[d >> 8], 1);
    }
  }
  __syncthreads();
  if (lc[t]) atomicAdd(&bc[t], lc[t]);
}

template <int VPT>
__global__ __launch_bounds__(256) void bucket_scatter_kernel(const int* __restrict__ ei, int E,
                                                             int n,
                                                             const int* __restrict__ bcnt,
                                                             int* __restrict__ bcur_rel,
                                                             unsigned* __restrict__ entries,
                                                             int B) {
  __shared__ int lc[256];
  __shared__ int lbase[256];
  __shared__ int bscan[256];
  int t = threadIdx.x;
  lc[t] = 0;
  int v = (t < B) ? bcnt[t] : 0;
  bscan[t] = v;
  __syncthreads();
  for (int s = 1; s < 256; s <<= 1) {
    int a = (t >= s) ? bscan[t - s] : 0;
    __syncthreads();
    bscan[t] += a;
    __syncthreads();
  }
  int excl = bscan[t] - v;   // global base of bucket t

  int base = blockIdx.x * (256 * VPT) + t;
  int tot = E + n;
  int bb[VPT], ll[VPT];
  unsigned pk[VPT];
#pragma unroll
  for (int u = 0; u < VPT; ++u) {
    int i = base + u * 256;
    bb[u] = -1;
    if (i < tot) {
      int s, d;
      if (i < E) { s = ei[i]; d = ei[E + i]; }
      else       { s = d = i - E; }
      int b = d >> 8;
      bb[u] = b;
      ll[u] = atomicAdd(&lc[b], 1);
      pk[u] = (unsigned)s | ((unsigned)(d & 255) << 16);
    }
  }
  __syncthreads();
  if (lc[t]) lbase[t] = excl + atomicAdd(&bcur_rel[t], lc[t]);
  __syncthreads();
#pragma unroll
  for (int u = 0; u < VPT; ++u)
    if (bb[u] >= 0) entries[lbase[bb[u]] + ll[u]] = pk[u];
}

__global__ __launch_bounds__(256) void csr_build_kernel(const unsigned* __restrict__ entries,
                                                        const int* __restrict__ bcnt,
                                                        int* __restrict__ off,
                                                        unsigned short* __restrict__ eps,
                                                        int n, int B) {
  __shared__ int bscan[256];
  __shared__ int hist[256];
  __shared__ int scn[256];
  __shared__ int cur[256];
  int b = blockIdx.x, t = threadIdx.x;
  int v = (t < B) ? bcnt[t] : 0;
  bscan[t] = v;
  __syncthreads();
  for (int s = 1; s < 256; s <<= 1) {
    int a = (t >= s) ? bscan[t - s] : 0;
    __syncthreads();
    bscan[t] += a;
    __syncthreads();
  }
  int k0 = (b == 0) ? 0 : bscan[b - 1];
  int k1 = bscan[b];
  __syncthreads();

  hist[t] = 0;
  __syncthreads();
  for (int k = k0 + t; k < k1; k += 256) atomicAdd(&hist[(entries[k] >> 16) & 255], 1);
  __syncthreads();
  int hv = hist[t];
  scn[t] = hv;
  __syncthreads();
  for (int s = 1; s < 256; s <<= 1) {
    int a = (t >= s) ? scn[t - s] : 0;
    __syncthreads();
    scn[t] += a;
    __syncthreads();
  }
  int excl = scn[t] - hv;
  int d = (b << 8) + t;
  if (d < n) off[d] = k0 + excl;
  cur[t] = k0 + excl;
  __syncthreads();
  for (int k = k0 + t; k < k1; k += 256) {
    unsigned e = entries[k];
    unsigned dl = (e >> 16) & 255;
    int p = atomicAdd(&cur[dl], 1);
    eps[p] = (unsigned short)(e & 0xffffu);
  }
}

// ---------------- W prep: zero bcnt/bcur_rel + off[n] + W1 pack + v-vectors -

__global__ __launch_bounds__(256) void wprep_kernel(const float* __restrict__ W1,
                                                    const float* __restrict__ W2,
                                                    const float* __restrict__ as2,
                                                    const float* __restrict__ ad2,
                                                    const float* __restrict__ lw,
                                                    unsigned short* __restrict__ Wp1,
                                                    float* __restrict__ vsrc2,
                                                    float* __restrict__ vdst2,
                                                    float* __restrict__ vlin,
                                                    int* __restrict__ bcnt,
                                                    int* __restrict__ bcur_rel,
                                                    int* __restrict__ off,
                                                    int B, int n, int Etot) {
  if (blockIdx.x == 0) {
    if (threadIdx.x <= (unsigned)B) {
      bcnt[threadIdx.x] = 0;
      bcur_rel[threadIdx.x] = 0;
    }
    if (threadIdx.x == 255) off[n] = Etot;
  }
  int t = blockIdx.x * 256 + threadIdx.x;
  if (t < 16384) {
    int e = t;
    int i = e & 7;
    int c = (e >> 3) & 15;
    int g = (e >> 7) & 3;
    int kk = (e >> 9) & 3;
    int cn = e >> 11;
    int k = kk * 32 + g * 8 + i;
    int col = cn * 16 + c;
    __half h = __float2half(W1[k * 128 + col]);
    Wp1[e] = *(unsigned short*)&h;
  } else if (t < 16384 + 128) {
    int k = t - 16384;
    float a = 0.f, b = 0.f, s = 0.f;
    for (int cc = 0; cc < 64; ++cc) {
      float w = W2[k * 64 + cc];
      a = fmaf(w, as2[cc], a);
      b = fmaf(w, ad2[cc], b);
      s = fmaf(w, lw[cc], s);
    }
    vsrc2[k] = a;
    vdst2[k] = b;
    vlin[k] = s;
  }
}

// ---------------- MFMA GEMM1 + logits (LDS-staged A) ----------------

// block = 4 waves = 2M x 2N(head); 32 rows, N=128, H out fp8 e4m3.
__global__ __launch_bounds__(256) void gemm1_kernel(const float* __restrict__ X,
                                                    const uint4* __restrict__ Wp,
                                                    const float* __restrict__ a_src,
                                                    const float* __restrict__ a_dst,
                                                    unsigned char* __restrict__ Hout,
                                                    float2* __restrict__ als,
                                                    float2* __restrict__ ald, int n) {
  __shared__ float Xl[32 * 132];      // 32 rows x 128 f32, +4 pad (bank-friendly)
  __shared__ float lgt[2][2][2][16];  // [wm][head][src/dst][row]
  int t = threadIdx.x;
  int wave = t >> 6, lane = t & 63;
  int wm = wave >> 1, wn = wave & 1;
  int g = lane >> 4, c = lane & 15;
  int nb0 = blockIdx.x * 32;

  // ---- stage 32 rows coalesced (float4), padded rows of 132 floats ----
  {
    const float4* Xg = (const float4*)X;
    float4* Xs = (float4*)Xl;
#pragma unroll
    for (int u = 0; u < 4; ++u) {
      int idx = u * 256 + t;          // 0..1023 float4 slots
      int r = idx >> 5, c4 = idx & 31;
      int row = nb0 + r;
      int rc = row < n ? row : (n - 1);
      Xs[r * 33 + c4] = Xg[(size_t)rc * 32 + c4];
    }
  }
  __syncthreads();

  // ---- A fragments from LDS: row = wm*16+c, k = g*8 + i (+32*kk) ----
  f16x8 af[4];
  const float* xr = Xl + (wm * 16 + c) * 132 + g * 8;
#pragma unroll
  for (int kk = 0; kk < 4; ++kk) {
    float4 x0 = *(const float4*)(xr + kk * 32);
    float4 x1 = *(const float4*)(xr + kk * 32 + 4);
    union { f16x8 v; h16x2 p[4]; } A;
    A.p[0] = __builtin_amdgcn_cvt_pkrtz(x0.x, x0.y);
    A.p[1] = __builtin_amdgcn_cvt_pkrtz(x0.z, x0.w);
    A.p[2] = __builtin_amdgcn_cvt_pkrtz(x1.x, x1.y);
    A.p[3] = __builtin_amdgcn_cvt_pkrtz(x1.z, x1.w);
    af[kk] = A.v;
  }

  // ---- MFMA: 4 col-tiles x 4 k-steps ----
  f32x4 acc[4];
  f32x4 z = {0.f, 0.f, 0.f, 0.f};
#pragma unroll
  for (int cn = 0; cn < 4; ++cn) acc[cn] = z;
#pragma unroll
  for (int cn = 0; cn < 4; ++cn) {
    int cng = wn * 4 + cn;
#pragma unroll
    for (int kk = 0; kk < 4; ++kk) {
      union { uint4 u; f16x8 v; } B;
      B.u = Wp[(cng * 4 + kk) * 64 + lane];
      acc[cn] = __builtin_amdgcn_mfma_f32_16x16x32_f16(af[kk], B.v, acc[cn], 0, 0, 0);
    }
  }

  // ---- epilogue: fp8 H store + logit dots ----
  float asv[4], adv[4];
#pragma unroll
  for (int cn = 0; cn < 4; ++cn) {
    int col_l = wn * 64 + cn * 16 + c;
    asv[cn] = a_src[col_l];
    adv[cn] = a_dst[col_l];
  }
  float ps[4] = {0.f, 0.f, 0.f, 0.f};
  float pd[4] = {0.f, 0.f, 0.f, 0.f};
#pragma unroll
  for (int cn = 0; cn < 4; ++cn) {
#pragma unroll
    for (int r = 0; r < 4; ++r) {
      float v = acc[cn][r];
      ps[r] = fmaf(v, asv[cn], ps[r]);
      pd[r] = fmaf(v, adv[cn], pd[r]);
      int noder = nb0 + wm * 16 + g * 4 + r;
      int colg = wn * 64 + cn * 16 + c;
      if (noder < n) {
        int b8 = __builtin_amdgcn_cvt_pk_fp8_f32(v, v, 0, false);
        Hout[(size_t)noder * 128 + colg] = (unsigned char)(b8 & 0xff);
      }
    }
  }
#pragma unroll
  for (int r = 0; r < 4; ++r) {
#pragma unroll
    for (int m = 1; m <= 8; m <<= 1) {
      ps[r] += __shfl_xor(ps[r], m, 64);
      pd[r] += __shfl_xor(pd[r], m, 64);
    }
  }
  if (c == 0) {
#pragma unroll
    for (int r = 0; r < 4; ++r) {
      lgt[wm][wn][0][g * 4 + r] = ps[r];
      lgt[wm][wn][1][g * 4 + r] = pd[r];
    }
  }
  __syncthreads();
  if (t < 32) {
    int wmm = t >> 4, row = t & 15;
    int node = nb0 + wmm * 16 + row;
    if (node < n) {
      als[node] = make_float2(lgt[wmm][0][0][row], lgt[wmm][1][0][row]);
      ald[node] = make_float2(lgt[wmm][0][1][row], lgt[wmm][1][1][row]);
    }
  }
}

// ---------------- aggregation ----------------

// layer 1 (fp8 rows, 128B) + fused layer-2 projection epilogue (R19 loop).
__global__ __launch_bounds__(256) void agg1_kernel(const unsigned char* __restrict__ Hb8,
                                                   const float2* __restrict__ als,
                                                   const float2* __restrict__ ald,
                                                   const unsigned short* __restrict__ eps,
                                                   const int* __restrict__ off,
                                                   const float* __restrict__ b1,
                                                   const float* __restrict__ vsrc2,
                                                   const float* __restrict__ vdst2,
                                                   const float* __restrict__ vlin,
                                                   float2* __restrict__ gsrc,
                                                   float* __restrict__ adst2, int n) {
  __shared__ float wlds[4][128];
  int wid = (blockIdx.x * 256 + threadIdx.x) >> 6;
  int lane = threadIdx.x & 63;
  if (wid >= n) return;
  wid = __builtin_amdgcn_readfirstlane(wid);
  int wslot = (threadIdx.x >> 6) & 3;
  int half = lane >> 5;
  int k0 = off[wid], k1 = off[wid + 1];
  const unsigned short* Hu = (const unsigned short*)Hb8;
  float2 advv = ald[wid];
  float* wrow = &wlds[wslot][half << 6];

  float ax = 0.f, ay = 0.f, den = 0.f;

  for (int kb = k0; kb < k1; kb += 64) {
    int rem = min(k1 - kb, 64);
    int e = kb + (lane < rem ? lane : rem - 1);
    unsigned pp = eps[e];
    float2 l = als[pp];
    float g0 = __expf(LEAKY(l.x + advv.x));
    float g1 = __expf(LEAKY(l.y + advv.y));
    wlds[wslot][lane] = g0;
    wlds[wslot][64 + lane] = g1;

#define EDGE1(jj)                                                                   \
  {                                                                                 \
    unsigned p = (unsigned)__builtin_amdgcn_readlane((int)pp, (jj));                \
    float w = wrow[(jj)];                                                           \
    unsigned short hv = Hu[(p << 6) | (unsigned)lane];                              \
    v2f hf = __builtin_amdgcn_cvt_pk_f32_fp8((int)hv, false);                       \
    den += w;                                                                       \
    ax = fmaf(hf.x, w, ax);                                                         \
    ay = fmaf(hf.y, w, ay);                                                         \
  }

    int nb = rem >> 3;
    for (int b = 0; b < nb; ++b) {
      int jb = b << 3;
#pragma unroll
      for (int j = 0; j < 8; ++j) EDGE1(jb + j);
    }
    for (int jj = nb << 3; jj < rem; ++jj) EDGE1(jj);
#undef EDGE1
  }

  // elu(out + b1), then project onto the three layer-2 vectors.
  float inv = 1.f / (den + 1e-16f);
  float2 bv = ((const float2*)b1)[lane];
  float r0 = ax * inv + bv.x;
  float r1 = ay * inv + bv.y;
  r0 = r0 > 0.f ? r0 : (__expf(r0) - 1.f);
  r1 = r1 > 0.f ? r1 : (__expf(r1) - 1.f);
  float2 vs = ((const float2*)vsrc2)[lane];
  float2 vd = ((const float2*)vdst2)[lane];
  float2 vl = ((const float2*)vlin)[lane];
  float ps = r0 * vs.x + r1 * vs.y;
  float pd = r0 * vd.x + r1 * vd.y;
  float sv = r0 * vl.x + r1 * vl.y;
#pragma unroll
  for (int m = 1; m <= 32; m <<= 1) {
    ps += __shfl_xor(ps, m, 64);
    pd += __shfl_xor(pd, m, 64);
    sv += __shfl_xor(sv, m, 64);
  }
  if (lane == 0) {
    gsrc[wid] = make_float2(ps, sv);
    adst2[wid] = pd;
  }
}

// layer 2 + head, collapsed: per edge gather (logit_src, s) float2; scalar agg.
__global__ __launch_bounds__(256) void agg2_kernel(const float2* __restrict__ gsrc,
                                                   const float* __restrict__ adst2,
                                                   const unsigned short* __restrict__ eps,
                                                   const int* __restrict__ off,
                                                   const float* __restrict__ b2,
                                                   const float* __restrict__ lin_w,
                                                   const float* __restrict__ lin_b,
                                                   float* __restrict__ out, int n) {
  int wid = (blockIdx.x * 256 + threadIdx.x) >> 6;
  int lane = threadIdx.x & 63;
  if (wid >= n) return;
  wid = __builtin_amdgcn_readfirstlane(wid);
  int k0 = off[wid], k1 = off[wid + 1];
  float adv = adst2[wid];

  float num = 0.f, den = 0.f;
  for (int kb = k0; kb < k1; kb += 64) {
    int e = kb + lane;
    bool ok = e < k1;
    unsigned pp = eps[ok ? e : k0];
    float2 g = gsrc[pp];
    float w = ok ? __expf(LEAKY(g.x + adv)) : 0.f;
    num = fmaf(w, g.y, num);
    den += w;
  }
  float bt = b2[lane] * lin_w[lane];  // lanes cover all 64 ch -> b2.lin_w
#pragma unroll
  for (int m = 1; m <= 32; m <<= 1) {
    num += __shfl_xor(num, m, 64);
    den += __shfl_xor(den, m, 64);
    bt  += __shfl_xor(bt, m, 64);
  }
  if (lane == 0) out[wid] = num / (den + 1e-16f) + bt + lin_b[0];
}

// ---------------- launcher ----------------

static inline size_t alignup(size_t v) { return (v + 255) & ~(size_t)255; }

extern "C" void kernel_launch(void* const* d_in, const int* in_sizes, int n_in,
                              void* d_out, int out_size, void* d_ws, size_t ws_size,
                              hipStream_t stream) {
  const float* x   = (const float*)d_in[0];
  const int*   ei  = (const int*)d_in[1];
  const float* W1  = (const float*)d_in[2];
  const float* as1 = (const float*)d_in[3];
  const float* ad1 = (const float*)d_in[4];
  const float* b1  = (const float*)d_in[5];
  const float* W2  = (const float*)d_in[6];
  const float* as2 = (const float*)d_in[7];
  const float* ad2 = (const float*)d_in[8];
  const float* b2  = (const float*)d_in[9];
  const float* lw  = (const float*)d_in[10];
  const float* lb  = (const float*)d_in[11];
  float* out = (float*)d_out;

  const int N = out_size;          // 50000
  const int E = in_sizes[1] / 2;   // 1600000
  const int Etot = E + N;
  const int B = (N + 255) >> 8;    // 196 buckets

  char* p = (char*)d_ws;
  int* bcnt = (int*)p;  p += alignup((size_t)(B + 1) * 4);
  int* bcur_rel = (int*)p; p += alignup((size_t)(B + 1) * 4);
  unsigned* entries = (unsigned*)p; p += alignup((size_t)Etot * 4);
  int* off  = (int*)p;  p += alignup((size_t)(N + 1) * 4);
  unsigned short* eps = (unsigned short*)p; p += alignup((size_t)Etot * 2);
  float2* als = (float2*)p; p += alignup((size_t)N * 8);
  float2* ald = (float2*)p; p += alignup((size_t)N * 8);
  float2* gsrc = (float2*)p; p += alignup((size_t)N * 8);
  float* adst2 = (float*)p; p += alignup((size_t)N * 4);
  unsigned char* h1b = (unsigned char*)p; p += alignup((size_t)N * 128);
  unsigned short* wp1 = (unsigned short*)p; p += alignup((size_t)16384 * 2);
  float* vsrc2 = (float*)p; p += alignup((size_t)128 * 4);
  float* vdst2 = (float*)p; p += alignup((size_t)128 * 4);
  float* vlin  = (float*)p; p += alignup((size_t)128 * 4);

  constexpr int VPT = 8;
  int egrid = (Etot + 256 * VPT - 1) / (256 * VPT);

  wprep_kernel<<<65, 256, 0, stream>>>(W1, W2, as2, ad2, lw, wp1, vsrc2, vdst2, vlin,
                                       bcnt, bcur_rel, off, B, N, Etot);
  bucket_cnt_kernel<VPT><<<egrid, 256, 0, stream>>>(ei, E, N, bcnt);
  bucket_scatter_kernel<VPT><<<egrid, 256, 0, stream>>>(ei, E, N, bcnt, bcur_rel,
                                                        entries, B);
  csr_build_kernel<<<B, 256, 0, stream>>>(entries, bcnt, off, eps, N, B);

  gemm1_kernel<<<(N + 31) / 32, 256, 0, stream>>>(
      x, (const uint4*)wp1, as1, ad1, h1b, als, ald, N);
  agg1_kernel<<<(N + 3) / 4, 256, 0, stream>>>(h1b, als, ald, eps, off, b1,
                                               vsrc2, vdst2, vlin, gsrc, adst2, N);
  agg2_kernel<<<(N + 3) / 4, 256, 0, stream>>>(gsrc, adst2, eps, off, b2, lw, lb, out, N);
}

// Round 15
// 133.162 us; speedup vs baseline: 2.2219x; 1.0960x over previous
//
#include <hip/hip_runtime.h>
#include <hip/hip_fp16.h>

// GAT regression: 2-layer GAT + linear head.
// R22: dispatch fusion/overlap. D0 zero(bcnt,bcur_rel,off[n]); D1 = wprep
//      (blocks 0..64) + bucket_cnt (rest) fused — independent work, one
//      dispatch; D2 = gemm1 (blocks 0..gb-1) + bucket_scatter (rest) fused —
//      both only need D1's outputs, run CONCURRENTLY (gemm1 hides under
//      scatter); D3 = csr_build at 512 threads (halves per-bucket serial
//      depth; was 12% occupancy); D4 = agg1; D5 = agg2. 7 dispatches -> 6,
//      with the two mid-pipeline kernels overlapped.
// R21 retained: local bucket scans (no bucket_scan kernel), u16 eps, gemm2
//      deleted (projection vectors in agg1 epilogue), MFMA gemm1 LDS-staged,
//      fp8 e4m3 H1 rows, in-agg softmax weights, scalar agg2.
// Requires N < 65536 (16-bit packing). N = 50000.

#define LEAKY(x) ((x) > 0.f ? (x) : 0.2f * (x))

typedef float v2f __attribute__((ext_vector_type(2)));
typedef _Float16 f16x8 __attribute__((ext_vector_type(8)));
typedef __fp16 h16x2 __attribute__((ext_vector_type(2)));
typedef float f32x4 __attribute__((ext_vector_type(4)));

// ---------------- D0: zero control arrays ----------------

__global__ __launch_bounds__(256) void zero_kernel(int* __restrict__ bcnt,
                                                   int* __restrict__ bcur_rel,
                                                   int* __restrict__ off,
                                                   int B, int n, int Etot) {
  if (threadIdx.x <= (unsigned)B) {
    bcnt[threadIdx.x] = 0;
    bcur_rel[threadIdx.x] = 0;
  }
  if (threadIdx.x == 255) off[n] = Etot;
}

// ---------------- D1: wprep + bucket_cnt (fused, disjoint blocks) -----------

template <int VPT>
__global__ __launch_bounds__(256) void prep_cnt_kernel(const float* __restrict__ W1,
                                                       const float* __restrict__ W2,
                                                       const float* __restrict__ as2,
                                                       const float* __restrict__ ad2,
                                                       const float* __restrict__ lw,
                                                       unsigned short* __restrict__ Wp1,
                                                       float* __restrict__ vsrc2,
                                                       float* __restrict__ vdst2,
                                                       float* __restrict__ vlin,
                                                       const int* __restrict__ ei, int E, int n,
                                                       int* __restrict__ bc, int WB) {
  if ((int)blockIdx.x < WB) {
    int t = blockIdx.x * 256 + threadIdx.x;
    if (t < 16384) {
      int e = t;
      int i = e & 7;
      int c = (e >> 3) & 15;
      int g = (e >> 7) & 3;
      int kk = (e >> 9) & 3;
      int cn = e >> 11;
      int k = kk * 32 + g * 8 + i;
      int col = cn * 16 + c;
      __half h = __float2half(W1[k * 128 + col]);
      Wp1[e] = *(unsigned short*)&h;
    } else if (t < 16384 + 128) {
      int k = t - 16384;
      float a = 0.f, b = 0.f, s = 0.f;
      for (int cc = 0; cc < 64; ++cc) {
        float w = W2[k * 64 + cc];
        a = fmaf(w, as2[cc], a);
        b = fmaf(w, ad2[cc], b);
        s = fmaf(w, lw[cc], s);
      }
      vsrc2[k] = a;
      vdst2[k] = b;
      vlin[k] = s;
    }
    return;
  }
  // ---- bucket_cnt part ----
  __shared__ int lc[256];
  int t = threadIdx.x;
  lc[t] = 0;
  __syncthreads();
  int base = (blockIdx.x - WB) * (256 * VPT) + t;
  int tot = E + n;
#pragma unroll
  for (int u = 0; u < VPT; ++u) {
    int i = base + u * 256;
    if (i < tot) {
      int d = (i < E) ? ei[E + i] : (i - E);
      atomicAdd(&lc[d >> 8], 1);
    }
  }
  __syncthreads();
  if (lc[t]) atomicAdd(&bc[t], lc[t]);
}

// ---------------- D2: gemm1 + bucket_scatter (fused, concurrent) ------------

template <int VPT>
__global__ __launch_bounds__(256) void gemm_scatter_kernel(
    const float* __restrict__ X, const uint4* __restrict__ Wp,
    const float* __restrict__ a_src, const float* __restrict__ a_dst,
    unsigned char* __restrict__ Hout, float2* __restrict__ als, float2* __restrict__ ald,
    const int* __restrict__ ei, int E, int n,
    const int* __restrict__ bcnt, int* __restrict__ bcur_rel,
    unsigned* __restrict__ entries, int B, int GB) {
  if ((int)blockIdx.x < GB) {
    // ================= gemm1 =================
    __shared__ float Xl[32 * 132];
    __shared__ float lgt[2][2][2][16];
    int t = threadIdx.x;
    int wave = t >> 6, lane = t & 63;
    int wm = wave >> 1, wn = wave & 1;
    int g = lane >> 4, c = lane & 15;
    int nb0 = blockIdx.x * 32;

    {
      const float4* Xg = (const float4*)X;
      float4* Xs = (float4*)Xl;
#pragma unroll
      for (int u = 0; u < 4; ++u) {
        int idx = u * 256 + t;
        int r = idx >> 5, c4 = idx & 31;
        int row = nb0 + r;
        int rc = row < n ? row : (n - 1);
        Xs[r * 33 + c4] = Xg[(size_t)rc * 32 + c4];
      }
    }
    __syncthreads();

    f16x8 af[4];
    const float* xr = Xl + (wm * 16 + c) * 132 + g * 8;
#pragma unroll
    for (int kk = 0; kk < 4; ++kk) {
      float4 x0 = *(const float4*)(xr + kk * 32);
      float4 x1 = *(const float4*)(xr + kk * 32 + 4);
      union { f16x8 v; h16x2 p[4]; } A;
      A.p[0] = __builtin_amdgcn_cvt_pkrtz(x0.x, x0.y);
      A.p[1] = __builtin_amdgcn_cvt_pkrtz(x0.z, x0.w);
      A.p[2] = __builtin_amdgcn_cvt_pkrtz(x1.x, x1.y);
      A.p[3] = __builtin_amdgcn_cvt_pkrtz(x1.z, x1.w);
      af[kk] = A.v;
    }

    f32x4 acc[4];
    f32x4 z = {0.f, 0.f, 0.f, 0.f};
#pragma unroll
    for (int cn = 0; cn < 4; ++cn) acc[cn] = z;
#pragma unroll
    for (int cn = 0; cn < 4; ++cn) {
      int cng = wn * 4 + cn;
#pragma unroll
      for (int kk = 0; kk < 4; ++kk) {
        union { uint4 u; f16x8 v; } Bf;
        Bf.u = Wp[(cng * 4 + kk) * 64 + lane];
        acc[cn] = __builtin_amdgcn_mfma_f32_16x16x32_f16(af[kk], Bf.v, acc[cn], 0, 0, 0);
      }
    }

    float asv[4], adv[4];
#pragma unroll
    for (int cn = 0; cn < 4; ++cn) {
      int col_l = wn * 64 + cn * 16 + c;
      asv[cn] = a_src[col_l];
      adv[cn] = a_dst[col_l];
    }
    float ps[4] = {0.f, 0.f, 0.f, 0.f};
    float pd[4] = {0.f, 0.f, 0.f, 0.f};
#pragma unroll
    for (int cn = 0; cn < 4; ++cn) {
#pragma unroll
      for (int r = 0; r < 4; ++r) {
        float v = acc[cn][r];
        ps[r] = fmaf(v, asv[cn], ps[r]);
        pd[r] = fmaf(v, adv[cn], pd[r]);
        int noder = nb0 + wm * 16 + g * 4 + r;
        int colg = wn * 64 + cn * 16 + c;
        if (noder < n) {
          int b8 = __builtin_amdgcn_cvt_pk_fp8_f32(v, v, 0, false);
          Hout[(size_t)noder * 128 + colg] = (unsigned char)(b8 & 0xff);
        }
      }
    }
#pragma unroll
    for (int r = 0; r < 4; ++r) {
#pragma unroll
      for (int m = 1; m <= 8; m <<= 1) {
        ps[r] += __shfl_xor(ps[r], m, 64);
        pd[r] += __shfl_xor(pd[r], m, 64);
      }
    }
    if (c == 0) {
#pragma unroll
      for (int r = 0; r < 4; ++r) {
        lgt[wm][wn][0][g * 4 + r] = ps[r];
        lgt[wm][wn][1][g * 4 + r] = pd[r];
      }
    }
    __syncthreads();
    if (t < 32) {
      int wmm = t >> 4, row = t & 15;
      int node = nb0 + wmm * 16 + row;
      if (node < n) {
        als[node] = make_float2(lgt[wmm][0][0][row], lgt[wmm][1][0][row]);
        ald[node] = make_float2(lgt[wmm][0][1][row], lgt[wmm][1][1][row]);
      }
    }
    return;
  }
  // ================= bucket_scatter =================
  __shared__ int lc[256];
  __shared__ int lbase[256];
  __shared__ int bscan[256];
  int t = threadIdx.x;
  lc[t] = 0;
  int v = (t < B) ? bcnt[t] : 0;
  bscan[t] = v;
  __syncthreads();
  for (int s = 1; s < 256; s <<= 1) {
    int a = (t >= s) ? bscan[t - s] : 0;
    __syncthreads();
    bscan[t] += a;
    __syncthreads();
  }
  int excl = bscan[t] - v;

  int base = (blockIdx.x - GB) * (256 * VPT) + t;
  int tot = E + n;
  int bb[VPT], ll[VPT];
  unsigned pk[VPT];
#pragma unroll
  for (int u = 0; u < VPT; ++u) {
    int i = base + u * 256;
    bb[u] = -1;
    if (i < tot) {
      int s, d;
      if (i < E) { s = ei[i]; d = ei[E + i]; }
      else       { s = d = i - E; }
      int b = d >> 8;
      bb[u] = b;
      ll[u] = atomicAdd(&lc[b], 1);
      pk[u] = (unsigned)s | ((unsigned)(d & 255) << 16);
    }
  }
  __syncthreads();
  if (lc[t]) lbase[t] = excl + atomicAdd(&bcur_rel[t], lc[t]);
  __syncthreads();
#pragma unroll
  for (int u = 0; u < VPT; ++u)
    if (bb[u] >= 0) entries[lbase[bb[u]] + ll[u]] = pk[u];
}

// ---------------- D3: csr_build at 512 threads ----------------

__global__ __launch_bounds__(512) void csr_build_kernel(const unsigned* __restrict__ entries,
                                                        const int* __restrict__ bcnt,
                                                        int* __restrict__ off,
                                                        unsigned short* __restrict__ eps,
                                                        int n, int B) {
  __shared__ int bscan[256];
  __shared__ int hist[256];
  __shared__ int scn[256];
  __shared__ int cur[256];
  int b = blockIdx.x, t = threadIdx.x;
  if (t < 256) bscan[t] = (t < B) ? bcnt[t] : 0;
  __syncthreads();
  for (int s = 1; s < 256; s <<= 1) {
    int a = (t >= (unsigned)s && t < 256) ? bscan[t - s] : 0;
    __syncthreads();
    if (t < 256) bscan[t] += a;
    __syncthreads();
  }
  int k0 = (b == 0) ? 0 : bscan[b - 1];
  int k1 = bscan[b];

  if (t < 256) hist[t] = 0;
  __syncthreads();
  for (int k = k0 + t; k < k1; k += 512) atomicAdd(&hist[(entries[k] >> 16) & 255], 1);
  __syncthreads();
  int hv = (t < 256) ? hist[t] : 0;
  if (t < 256) scn[t] = hv;
  __syncthreads();
  for (int s = 1; s < 256; s <<= 1) {
    int a = (t >= (unsigned)s && t < 256) ? scn[t - s] : 0;
    __syncthreads();
    if (t < 256) scn[t] += a;
    __syncthreads();
  }
  if (t < 256) {
    int excl = scn[t] - hv;
    int d = (b << 8) + t;
    if (d < n) off[d] = k0 + excl;
    cur[t] = k0 + excl;
  }
  __syncthreads();
  for (int k = k0 + t; k < k1; k += 512) {
    unsigned e = entries[k];
    unsigned dl = (e >> 16) & 255;
    int p = atomicAdd(&cur[dl], 1);
    eps[p] = (unsigned short)(e & 0xffffu);
  }
}

// ---------------- D4: agg1 (R19/R21 structure) ----------------

__global__ __launch_bounds__(256) void agg1_kernel(const unsigned char* __restrict__ Hb8,
                                                   const float2* __restrict__ als,
                                                   const float2* __restrict__ ald,
                                                   const unsigned short* __restrict__ eps,
                                                   const int* __restrict__ off,
                                                   const float* __restrict__ b1,
                                                   const float* __restrict__ vsrc2,
                                                   const float* __restrict__ vdst2,
                                                   const float* __restrict__ vlin,
                                                   float2* __restrict__ gsrc,
                                                   float* __restrict__ adst2, int n) {
  __shared__ float wlds[4][128];
  int wid = (blockIdx.x * 256 + threadIdx.x) >> 6;
  int lane = threadIdx.x & 63;
  if (wid >= n) return;
  wid = __builtin_amdgcn_readfirstlane(wid);
  int wslot = (threadIdx.x >> 6) & 3;
  int half = lane >> 5;
  int k0 = off[wid], k1 = off[wid + 1];
  const unsigned short* Hu = (const unsigned short*)Hb8;
  float2 advv = ald[wid];
  float* wrow = &wlds[wslot][half << 6];

  float ax = 0.f, ay = 0.f, den = 0.f;

  for (int kb = k0; kb < k1; kb += 64) {
    int rem = min(k1 - kb, 64);
    int e = kb + (lane < rem ? lane : rem - 1);
    unsigned pp = eps[e];
    float2 l = als[pp];
    float g0 = __expf(LEAKY(l.x + advv.x));
    float g1 = __expf(LEAKY(l.y + advv.y));
    wlds[wslot][lane] = g0;
    wlds[wslot][64 + lane] = g1;

#define EDGE1(jj)                                                                   \
  {                                                                                 \
    unsigned p = (unsigned)__builtin_amdgcn_readlane((int)pp, (jj));                \
    float w = wrow[(jj)];                                                           \
    unsigned short hv = Hu[(p << 6) | (unsigned)lane];                              \
    v2f hf = __builtin_amdgcn_cvt_pk_f32_fp8((int)hv, false);                       \
    den += w;                                                                       \
    ax = fmaf(hf.x, w, ax);                                                         \
    ay = fmaf(hf.y, w, ay);                                                         \
  }

    int nb = rem >> 3;
    for (int b = 0; b < nb; ++b) {
      int jb = b << 3;
#pragma unroll
      for (int j = 0; j < 8; ++j) EDGE1(jb + j);
    }
    for (int jj = nb << 3; jj < rem; ++jj) EDGE1(jj);
#undef EDGE1
  }

  float inv = 1.f / (den + 1e-16f);
  float2 bv = ((const float2*)b1)[lane];
  float r0 = ax * inv + bv.x;
  float r1 = ay * inv + bv.y;
  r0 = r0 > 0.f ? r0 : (__expf(r0) - 1.f);
  r1 = r1 > 0.f ? r1 : (__expf(r1) - 1.f);
  float2 vs = ((const float2*)vsrc2)[lane];
  float2 vd = ((const float2*)vdst2)[lane];
  float2 vl = ((const float2*)vlin)[lane];
  float ps = r0 * vs.x + r1 * vs.y;
  float pd = r0 * vd.x + r1 * vd.y;
  float sv = r0 * vl.x + r1 * vl.y;
#pragma unroll
  for (int m = 1; m <= 32; m <<= 1) {
    ps += __shfl_xor(ps, m, 64);
    pd += __shfl_xor(pd, m, 64);
    sv += __shfl_xor(sv, m, 64);
  }
  if (lane == 0) {
    gsrc[wid] = make_float2(ps, sv);
    adst2[wid] = pd;
  }
}

// ---------------- D5: agg2 ----------------

__global__ __launch_bounds__(256) void agg2_kernel(const float2* __restrict__ gsrc,
                                                   const float* __restrict__ adst2,
                                                   const unsigned short* __restrict__ eps,
                                                   const int* __restrict__ off,
                                                   const float* __restrict__ b2,
                                                   const float* __restrict__ lin_w,
                                                   const float* __restrict__ lin_b,
                                                   float* __restrict__ out, int n) {
  int wid = (blockIdx.x * 256 + threadIdx.x) >> 6;
  int lane = threadIdx.x & 63;
  if (wid >= n) return;
  wid = __builtin_amdgcn_readfirstlane(wid);
  int k0 = off[wid], k1 = off[wid + 1];
  float adv = adst2[wid];

  float num = 0.f, den = 0.f;
  for (int kb = k0; kb < k1; kb += 64) {
    int e = kb + lane;
    bool ok = e < k1;
    unsigned pp = eps[ok ? e : k0];
    float2 g = gsrc[pp];
    float w = ok ? __expf(LEAKY(g.x + adv)) : 0.f;
    num = fmaf(w, g.y, num);
    den += w;
  }
  float bt = b2[lane] * lin_w[lane];
#pragma unroll
  for (int m = 1; m <= 32; m <<= 1) {
    num += __shfl_xor(num, m, 64);
    den += __shfl_xor(den, m, 64);
    bt  += __shfl_xor(bt, m, 64);
  }
  if (lane == 0) out[wid] = num / (den + 1e-16f) + bt + lin_b[0];
}

// ---------------- launcher ----------------

static inline size_t alignup(size_t v) { return (v + 255) & ~(size_t)255; }

extern "C" void kernel_launch(void* const* d_in, const int* in_sizes, int n_in,
                              void* d_out, int out_size, void* d_ws, size_t ws_size,
                              hipStream_t stream) {
  const float* x   = (const float*)d_in[0];
  const int*   ei  = (const int*)d_in[1];
  const float* W1  = (const float*)d_in[2];
  const float* as1 = (const float*)d_in[3];
  const float* ad1 = (const float*)d_in[4];
  const float* b1  = (const float*)d_in[5];
  const float* W2  = (const float*)d_in[6];
  const float* as2 = (const float*)d_in[7];
  const float* ad2 = (const float*)d_in[8];
  const float* b2  = (const float*)d_in[9];
  const float* lw  = (const float*)d_in[10];
  const float* lb  = (const float*)d_in[11];
  float* out = (float*)d_out;

  const int N = out_size;          // 50000
  const int E = in_sizes[1] / 2;   // 1600000
  const int Etot = E + N;
  const int B = (N + 255) >> 8;    // 196 buckets

  char* p = (char*)d_ws;
  int* bcnt = (int*)p;  p += alignup((size_t)(B + 1) * 4);
  int* bcur_rel = (int*)p; p += alignup((size_t)(B + 1) * 4);
  unsigned* entries = (unsigned*)p; p += alignup((size_t)Etot * 4);
  int* off  = (int*)p;  p += alignup((size_t)(N + 1) * 4);
  unsigned short* eps = (unsigned short*)p; p += alignup((size_t)Etot * 2);
  float2* als = (float2*)p; p += alignup((size_t)N * 8);
  float2* ald = (float2*)p; p += alignup((size_t)N * 8);
  float2* gsrc = (float2*)p; p += alignup((size_t)N * 8);
  float* adst2 = (float*)p; p += alignup((size_t)N * 4);
  unsigned char* h1b = (unsigned char*)p; p += alignup((size_t)N * 128);
  unsigned short* wp1 = (unsigned short*)p; p += alignup((size_t)16384 * 2);
  float* vsrc2 = (float*)p; p += alignup((size_t)128 * 4);
  float* vdst2 = (float*)p; p += alignup((size_t)128 * 4);
  float* vlin  = (float*)p; p += alignup((size_t)128 * 4);

  constexpr int VPT = 8;
  int egrid = (Etot + 256 * VPT - 1) / (256 * VPT);
  constexpr int WB = 65;                 // wprep blocks
  int GB = (N + 31) / 32;                // gemm1 blocks

  zero_kernel<<<1, 256, 0, stream>>>(bcnt, bcur_rel, off, B, N, Etot);
  prep_cnt_kernel<VPT><<<WB + egrid, 256, 0, stream>>>(
      W1, W2, as2, ad2, lw, wp1, vsrc2, vdst2, vlin, ei, E, N, bcnt, WB);
  gemm_scatter_kernel<VPT><<<GB + egrid, 256, 0, stream>>>(
      x, (const uint4*)wp1, as1, ad1, h1b, als, ald,
      ei, E, N, bcnt, bcur_rel, entries, B, GB);
  csr_build_kernel<<<B, 512, 0, stream>>>(entries, bcnt, off, eps, N, B);

  agg1_kernel<<<(N + 3) / 4, 256, 0, stream>>>(h1b, als, ald, eps, off, b1,
                                               vsrc2, vdst2, vlin, gsrc, adst2, N);
  agg2_kernel<<<(N + 3) / 4, 256, 0, stream>>>(gsrc, adst2, eps, off, b2, lw, lb, out, N);
}

// Round 16
// 130.607 us; speedup vs baseline: 2.2654x; 1.0196x over previous
//
#include <hip/hip_runtime.h>
#include <hip/hip_fp16.h>

// GAT regression: 2-layer GAT + linear head.
// R23: (1) agg1 den-add removed from the FMA loop (was 1 of 5 VALU/edge,
//      64-way redundant): weight phase accumulates per-lane den partials
//      (own edge only, wave-uniform-masked) + ONE 12-shfl butterfly after the
//      loop (R20's regression was the per-chunk in-loop butterfly).
//      (2) csr_build at 1024 threads (196 blocks < 1/CU; halves serial depth).
// R22 retained: fused D1 (wprep+bucket_cnt), fused D2 (gemm1+bucket_scatter,
//      concurrent), local bucket scans, u16 eps, gemm2 deleted (projection
//      vectors in agg1 epilogue), MFMA gemm1 LDS-staged, fp8 e4m3 H1 rows,
//      in-agg softmax weights, scalar agg2.
// Requires N < 65536 (16-bit packing). N = 50000.

#define LEAKY(x) ((x) > 0.f ? (x) : 0.2f * (x))

typedef float v2f __attribute__((ext_vector_type(2)));
typedef _Float16 f16x8 __attribute__((ext_vector_type(8)));
typedef __fp16 h16x2 __attribute__((ext_vector_type(2)));
typedef float f32x4 __attribute__((ext_vector_type(4)));

// ---------------- D0: zero control arrays ----------------

__global__ __launch_bounds__(256) void zero_kernel(int* __restrict__ bcnt,
                                                   int* __restrict__ bcur_rel,
                                                   int* __restrict__ off,
                                                   int B, int n, int Etot) {
  if (threadIdx.x <= (unsigned)B) {
    bcnt[threadIdx.x] = 0;
    bcur_rel[threadIdx.x] = 0;
  }
  if (threadIdx.x == 255) off[n] = Etot;
}

// ---------------- D1: wprep + bucket_cnt (fused, disjoint blocks) -----------

template <int VPT>
__global__ __launch_bounds__(256) void prep_cnt_kernel(const float* __restrict__ W1,
                                                       const float* __restrict__ W2,
                                                       const float* __restrict__ as2,
                                                       const float* __restrict__ ad2,
                                                       const float* __restrict__ lw,
                                                       unsigned short* __restrict__ Wp1,
                                                       float* __restrict__ vsrc2,
                                                       float* __restrict__ vdst2,
                                                       float* __restrict__ vlin,
                                                       const int* __restrict__ ei, int E, int n,
                                                       int* __restrict__ bc, int WB) {
  if ((int)blockIdx.x < WB) {
    int t = blockIdx.x * 256 + threadIdx.x;
    if (t < 16384) {
      int e = t;
      int i = e & 7;
      int c = (e >> 3) & 15;
      int g = (e >> 7) & 3;
      int kk = (e >> 9) & 3;
      int cn = e >> 11;
      int k = kk * 32 + g * 8 + i;
      int col = cn * 16 + c;
      __half h = __float2half(W1[k * 128 + col]);
      Wp1[e] = *(unsigned short*)&h;
    } else if (t < 16384 + 128) {
      int k = t - 16384;
      float a = 0.f, b = 0.f, s = 0.f;
      for (int cc = 0; cc < 64; ++cc) {
        float w = W2[k * 64 + cc];
        a = fmaf(w, as2[cc], a);
        b = fmaf(w, ad2[cc], b);
        s = fmaf(w, lw[cc], s);
      }
      vsrc2[k] = a;
      vdst2[k] = b;
      vlin[k] = s;
    }
    return;
  }
  // ---- bucket_cnt part ----
  __shared__ int lc[256];
  int t = threadIdx.x;
  lc[t] = 0;
  __syncthreads();
  int base = (blockIdx.x - WB) * (256 * VPT) + t;
  int tot = E + n;
#pragma unroll
  for (int u = 0; u < VPT; ++u) {
    int i = base + u * 256;
    if (i < tot) {
      int d = (i < E) ? ei[E + i] : (i - E);
      atomicAdd(&lc[d >> 8], 1);
    }
  }
  __syncthreads();
  if (lc[t]) atomicAdd(&bc[t], lc[t]);
}

// ---------------- D2: gemm1 + bucket_scatter (fused, concurrent) ------------

template <int VPT>
__global__ __launch_bounds__(256) void gemm_scatter_kernel(
    const float* __restrict__ X, const uint4* __restrict__ Wp,
    const float* __restrict__ a_src, const float* __restrict__ a_dst,
    unsigned char* __restrict__ Hout, float2* __restrict__ als, float2* __restrict__ ald,
    const int* __restrict__ ei, int E, int n,
    const int* __restrict__ bcnt, int* __restrict__ bcur_rel,
    unsigned* __restrict__ entries, int B, int GB) {
  if ((int)blockIdx.x < GB) {
    // ================= gemm1 =================
    __shared__ float Xl[32 * 132];
    __shared__ float lgt[2][2][2][16];
    int t = threadIdx.x;
    int wave = t >> 6, lane = t & 63;
    int wm = wave >> 1, wn = wave & 1;
    int g = lane >> 4, c = lane & 15;
    int nb0 = blockIdx.x * 32;

    {
      const float4* Xg = (const float4*)X;
      float4* Xs = (float4*)Xl;
#pragma unroll
      for (int u = 0; u < 4; ++u) {
        int idx = u * 256 + t;
        int r = idx >> 5, c4 = idx & 31;
        int row = nb0 + r;
        int rc = row < n ? row : (n - 1);
        Xs[r * 33 + c4] = Xg[(size_t)rc * 32 + c4];
      }
    }
    __syncthreads();

    f16x8 af[4];
    const float* xr = Xl + (wm * 16 + c) * 132 + g * 8;
#pragma unroll
    for (int kk = 0; kk < 4; ++kk) {
      float4 x0 = *(const float4*)(xr + kk * 32);
      float4 x1 = *(const float4*)(xr + kk * 32 + 4);
      union { f16x8 v; h16x2 p[4]; } A;
      A.p[0] = __builtin_amdgcn_cvt_pkrtz(x0.x, x0.y);
      A.p[1] = __builtin_amdgcn_cvt_pkrtz(x0.z, x0.w);
      A.p[2] = __builtin_amdgcn_cvt_pkrtz(x1.x, x1.y);
      A.p[3] = __builtin_amdgcn_cvt_pkrtz(x1.z, x1.w);
      af[kk] = A.v;
    }

    f32x4 acc[4];
    f32x4 z = {0.f, 0.f, 0.f, 0.f};
#pragma unroll
    for (int cn = 0; cn < 4; ++cn) acc[cn] = z;
#pragma unroll
    for (int cn = 0; cn < 4; ++cn) {
      int cng = wn * 4 + cn;
#pragma unroll
      for (int kk = 0; kk < 4; ++kk) {
        union { uint4 u; f16x8 v; } Bf;
        Bf.u = Wp[(cng * 4 + kk) * 64 + lane];
        acc[cn] = __builtin_amdgcn_mfma_f32_16x16x32_f16(af[kk], Bf.v, acc[cn], 0, 0, 0);
      }
    }

    float asv[4], adv[4];
#pragma unroll
    for (int cn = 0; cn < 4; ++cn) {
      int col_l = wn * 64 + cn * 16 + c;
      asv[cn] = a_src[col_l];
      adv[cn] = a_dst[col_l];
    }
    float ps[4] = {0.f, 0.f, 0.f, 0.f};
    float pd[4] = {0.f, 0.f, 0.f, 0.f};
#pragma unroll
    for (int cn = 0; cn < 4; ++cn) {
#pragma unroll
      for (int r = 0; r < 4; ++r) {
        float v = acc[cn][r];
        ps[r] = fmaf(v, asv[cn], ps[r]);
        pd[r] = fmaf(v, adv[cn], pd[r]);
        int noder = nb0 + wm * 16 + g * 4 + r;
        int colg = wn * 64 + cn * 16 + c;
        if (noder < n) {
          int b8 = __builtin_amdgcn_cvt_pk_fp8_f32(v, v, 0, false);
          Hout[(size_t)noder * 128 + colg] = (unsigned char)(b8 & 0xff);
        }
      }
    }
#pragma unroll
    for (int r = 0; r < 4; ++r) {
#pragma unroll
      for (int m = 1; m <= 8; m <<= 1) {
        ps[r] += __shfl_xor(ps[r], m, 64);
        pd[r] += __shfl_xor(pd[r], m, 64);
      }
    }
    if (c == 0) {
#pragma unroll
      for (int r = 0; r < 4; ++r) {
        lgt[wm][wn][0][g * 4 + r] = ps[r];
        lgt[wm][wn][1][g * 4 + r] = pd[r];
      }
    }
    __syncthreads();
    if (t < 32) {
      int wmm = t >> 4, row = t & 15;
      int node = nb0 + wmm * 16 + row;
      if (node < n) {
        als[node] = make_float2(lgt[wmm][0][0][row], lgt[wmm][1][0][row]);
        ald[node] = make_float2(lgt[wmm][0][1][row], lgt[wmm][1][1][row]);
      }
    }
    return;
  }
  // ================= bucket_scatter =================
  __shared__ int lc[256];
  __shared__ int lbase[256];
  __shared__ int bscan[256];
  int t = threadIdx.x;
  lc[t] = 0;
  int v = (t < B) ? bcnt[t] : 0;
  bscan[t] = v;
  __syncthreads();
  for (int s = 1; s < 256; s <<= 1) {
    int a = (t >= s) ? bscan[t - s] : 0;
    __syncthreads();
    bscan[t] += a;
    __syncthreads();
  }
  int excl = bscan[t] - v;

  int base = (blockIdx.x - GB) * (256 * VPT) + t;
  int tot = E + n;
  int bb[VPT], ll[VPT];
  unsigned pk[VPT];
#pragma unroll
  for (int u = 0; u < VPT; ++u) {
    int i = base + u * 256;
    bb[u] = -1;
    if (i < tot) {
      int s, d;
      if (i < E) { s = ei[i]; d = ei[E + i]; }
      else       { s = d = i - E; }
      int b = d >> 8;
      bb[u] = b;
      ll[u] = atomicAdd(&lc[b], 1);
      pk[u] = (unsigned)s | ((unsigned)(d & 255) << 16);
    }
  }
  __syncthreads();
  if (lc[t]) lbase[t] = excl + atomicAdd(&bcur_rel[t], lc[t]);
  __syncthreads();
#pragma unroll
  for (int u = 0; u < VPT; ++u)
    if (bb[u] >= 0) entries[lbase[bb[u]] + ll[u]] = pk[u];
}

// ---------------- D3: csr_build at 1024 threads ----------------

__global__ __launch_bounds__(1024) void csr_build_kernel(const unsigned* __restrict__ entries,
                                                         const int* __restrict__ bcnt,
                                                         int* __restrict__ off,
                                                         unsigned short* __restrict__ eps,
                                                         int n, int B) {
  __shared__ int bscan[256];
  __shared__ int hist[256];
  __shared__ int scn[256];
  __shared__ int cur[256];
  int b = blockIdx.x, t = threadIdx.x;
  if (t < 256) bscan[t] = (t < B) ? bcnt[t] : 0;
  __syncthreads();
  for (int s = 1; s < 256; s <<= 1) {
    int a = (t >= (unsigned)s && t < 256) ? bscan[t - s] : 0;
    __syncthreads();
    if (t < 256) bscan[t] += a;
    __syncthreads();
  }
  int k0 = (b == 0) ? 0 : bscan[b - 1];
  int k1 = bscan[b];

  if (t < 256) hist[t] = 0;
  __syncthreads();
  for (int k = k0 + t; k < k1; k += 1024) atomicAdd(&hist[(entries[k] >> 16) & 255], 1);
  __syncthreads();
  int hv = (t < 256) ? hist[t] : 0;
  if (t < 256) scn[t] = hv;
  __syncthreads();
  for (int s = 1; s < 256; s <<= 1) {
    int a = (t >= (unsigned)s && t < 256) ? scn[t - s] : 0;
    __syncthreads();
    if (t < 256) scn[t] += a;
    __syncthreads();
  }
  if (t < 256) {
    int excl = scn[t] - hv;
    int d = (b << 8) + t;
    if (d < n) off[d] = k0 + excl;
    cur[t] = k0 + excl;
  }
  __syncthreads();
  for (int k = k0 + t; k < k1; k += 1024) {
    unsigned e = entries[k];
    unsigned dl = (e >> 16) & 255;
    int p = atomicAdd(&cur[dl], 1);
    eps[p] = (unsigned short)(e & 0xffffu);
  }
}

// ---------------- D4: agg1 (den out of FMA loop) ----------------

__global__ __launch_bounds__(256) void agg1_kernel(const unsigned char* __restrict__ Hb8,
                                                   const float2* __restrict__ als,
                                                   const float2* __restrict__ ald,
                                                   const unsigned short* __restrict__ eps,
                                                   const int* __restrict__ off,
                                                   const float* __restrict__ b1,
                                                   const float* __restrict__ vsrc2,
                                                   const float* __restrict__ vdst2,
                                                   const float* __restrict__ vlin,
                                                   float2* __restrict__ gsrc,
                                                   float* __restrict__ adst2, int n) {
  __shared__ float wlds[4][128];
  int wid = (blockIdx.x * 256 + threadIdx.x) >> 6;
  int lane = threadIdx.x & 63;
  if (wid >= n) return;
  wid = __builtin_amdgcn_readfirstlane(wid);
  int wslot = (threadIdx.x >> 6) & 3;
  int half = lane >> 5;
  int k0 = off[wid], k1 = off[wid + 1];
  const unsigned short* Hu = (const unsigned short*)Hb8;
  float2 advv = ald[wid];
  float* wrow = &wlds[wslot][half << 6];

  float ax = 0.f, ay = 0.f, den0 = 0.f, den1 = 0.f;

  for (int kb = k0; kb < k1; kb += 64) {
    int rem = min(k1 - kb, 64);
    int e = kb + (lane < rem ? lane : rem - 1);
    unsigned pp = eps[e];
    float2 l = als[pp];
    float g0 = __expf(LEAKY(l.x + advv.x));
    float g1 = __expf(LEAKY(l.y + advv.y));
    wlds[wslot][lane] = g0;
    wlds[wslot][64 + lane] = g1;
    // den partials: each lane adds ONLY its own edge (mask only on tail chunk)
    if (rem == 64) {
      den0 += g0;
      den1 += g1;
    } else if (lane < rem) {
      den0 += g0;
      den1 += g1;
    }

#define EDGE1(jj)                                                                   \
  {                                                                                 \
    unsigned p = (unsigned)__builtin_amdgcn_readlane((int)pp, (jj));                \
    float w = wrow[(jj)];                                                           \
    unsigned short hv = Hu[(p << 6) | (unsigned)lane];                              \
    v2f hf = __builtin_amdgcn_cvt_pk_f32_fp8((int)hv, false);                       \
    ax = fmaf(hf.x, w, ax);                                                         \
    ay = fmaf(hf.y, w, ay);                                                         \
  }

    int nb = rem >> 3;
    for (int b = 0; b < nb; ++b) {
      int jb = b << 3;
#pragma unroll
      for (int j = 0; j < 8; ++j) EDGE1(jb + j);
    }
    for (int jj = nb << 3; jj < rem; ++jj) EDGE1(jj);
#undef EDGE1
  }

  // ONE den butterfly (amortized over the whole edge list)
#pragma unroll
  for (int m = 1; m <= 32; m <<= 1) {
    den0 += __shfl_xor(den0, m, 64);
    den1 += __shfl_xor(den1, m, 64);
  }
  float den = half ? den1 : den0;

  // elu(out + b1), then project onto the three layer-2 vectors.
  float inv = 1.f / (den + 1e-16f);
  float2 bv = ((const float2*)b1)[lane];
  float r0 = ax * inv + bv.x;
  float r1 = ay * inv + bv.y;
  r0 = r0 > 0.f ? r0 : (__expf(r0) - 1.f);
  r1 = r1 > 0.f ? r1 : (__expf(r1) - 1.f);
  float2 vs = ((const float2*)vsrc2)[lane];
  float2 vd = ((const float2*)vdst2)[lane];
  float2 vl = ((const float2*)vlin)[lane];
  float ps = r0 * vs.x + r1 * vs.y;
  float pd = r0 * vd.x + r1 * vd.y;
  float sv = r0 * vl.x + r1 * vl.y;
#pragma unroll
  for (int m = 1; m <= 32; m <<= 1) {
    ps += __shfl_xor(ps, m, 64);
    pd += __shfl_xor(pd, m, 64);
    sv += __shfl_xor(sv, m, 64);
  }
  if (lane == 0) {
    gsrc[wid] = make_float2(ps, sv);
    adst2[wid] = pd;
  }
}

// ---------------- D5: agg2 ----------------

__global__ __launch_bounds__(256) void agg2_kernel(const float2* __restrict__ gsrc,
                                                   const float* __restrict__ adst2,
                                                   const unsigned short* __restrict__ eps,
                                                   const int* __restrict__ off,
                                                   const float* __restrict__ b2,
                                                   const float* __restrict__ lin_w,
                                                   const float* __restrict__ lin_b,
                                                   float* __restrict__ out, int n) {
  int wid = (blockIdx.x * 256 + threadIdx.x) >> 6;
  int lane = threadIdx.x & 63;
  if (wid >= n) return;
  wid = __builtin_amdgcn_readfirstlane(wid);
  int k0 = off[wid], k1 = off[wid + 1];
  float adv = adst2[wid];

  float num = 0.f, den = 0.f;
  for (int kb = k0; kb < k1; kb += 64) {
    int e = kb + lane;
    bool ok = e < k1;
    unsigned pp = eps[ok ? e : k0];
    float2 g = gsrc[pp];
    float w = ok ? __expf(LEAKY(g.x + adv)) : 0.f;
    num = fmaf(w, g.y, num);
    den += w;
  }
  float bt = b2[lane] * lin_w[lane];
#pragma unroll
  for (int m = 1; m <= 32; m <<= 1) {
    num += __shfl_xor(num, m, 64);
    den += __shfl_xor(den, m, 64);
    bt  += __shfl_xor(bt, m, 64);
  }
  if (lane == 0) out[wid] = num / (den + 1e-16f) + bt + lin_b[0];
}

// ---------------- launcher ----------------

static inline size_t alignup(size_t v) { return (v + 255) & ~(size_t)255; }

extern "C" void kernel_launch(void* const* d_in, const int* in_sizes, int n_in,
                              void* d_out, int out_size, void* d_ws, size_t ws_size,
                              hipStream_t stream) {
  const float* x   = (const float*)d_in[0];
  const int*   ei  = (const int*)d_in[1];
  const float* W1  = (const float*)d_in[2];
  const float* as1 = (const float*)d_in[3];
  const float* ad1 = (const float*)d_in[4];
  const float* b1  = (const float*)d_in[5];
  const float* W2  = (const float*)d_in[6];
  const float* as2 = (const float*)d_in[7];
  const float* ad2 = (const float*)d_in[8];
  const float* b2  = (const float*)d_in[9];
  const float* lw  = (const float*)d_in[10];
  const float* lb  = (const float*)d_in[11];
  float* out = (float*)d_out;

  const int N = out_size;          // 50000
  const int E = in_sizes[1] / 2;   // 1600000
  const int Etot = E + N;
  const int B = (N + 255) >> 8;    // 196 buckets

  char* p = (char*)d_ws;
  int* bcnt = (int*)p;  p += alignup((size_t)(B + 1) * 4);
  int* bcur_rel = (int*)p; p += alignup((size_t)(B + 1) * 4);
  unsigned* entries = (unsigned*)p; p += alignup((size_t)Etot * 4);
  int* off  = (int*)p;  p += alignup((size_t)(N + 1) * 4);
  unsigned short* eps = (unsigned short*)p; p += alignup((size_t)Etot * 2);
  float2* als = (float2*)p; p += alignup((size_t)N * 8);
  float2* ald = (float2*)p; p += alignup((size_t)N * 8);
  float2* gsrc = (float2*)p; p += alignup((size_t)N * 8);
  float* adst2 = (float*)p; p += alignup((size_t)N * 4);
  unsigned char* h1b = (unsigned char*)p; p += alignup((size_t)N * 128);
  unsigned short* wp1 = (unsigned short*)p; p += alignup((size_t)16384 * 2);
  float* vsrc2 = (float*)p; p += alignup((size_t)128 * 4);
  float* vdst2 = (float*)p; p += alignup((size_t)128 * 4);
  float* vlin  = (float*)p; p += alignup((size_t)128 * 4);

  constexpr int VPT = 8;
  int egrid = (Etot + 256 * VPT - 1) / (256 * VPT);
  constexpr int WB = 65;                 // wprep blocks
  int GB = (N + 31) / 32;                // gemm1 blocks

  zero_kernel<<<1, 256, 0, stream>>>(bcnt, bcur_rel, off, B, N, Etot);
  prep_cnt_kernel<VPT><<<WB + egrid, 256, 0, stream>>>(
      W1, W2, as2, ad2, lw, wp1, vsrc2, vdst2, vlin, ei, E, N, bcnt, WB);
  gemm_scatter_kernel<VPT><<<GB + egrid, 256, 0, stream>>>(
      x, (const uint4*)wp1, as1, ad1, h1b, als, ald,
      ei, E, N, bcnt, bcur_rel, entries, B, GB);
  csr_build_kernel<<<B, 1024, 0, stream>>>(entries, bcnt, off, eps, N, B);

  agg1_kernel<<<(N + 3) / 4, 256, 0, stream>>>(h1b, als, ald, eps, off, b1,
                                               vsrc2, vdst2, vlin, gsrc, adst2, N);
  agg2_kernel<<<(N + 3) / 4, 256, 0, stream>>>(gsrc, adst2, eps, off, b2, lw, lb, out, N);
}

// Round 17
// 127.627 us; speedup vs baseline: 2.3183x; 1.0233x over previous
//
#include <hip/hip_runtime.h>
#include <hip/hip_fp16.h>

// GAT regression: 2-layer GAT + linear head.
// R24: agg1 gathers 2 EDGES PER WAVE-LOAD (dword/lane): lanes 0-31 = edge 2q,
//      lanes 32-63 = edge 2q+1, each lane loads 4 fp8 ch of its edge's row.
//      Halves VMEM instructions at same bytes -> doubles edge throughput under
//      the measured MLP bound (6 schedule variants pinned at 44us; VALU cuts
//      were neutral => loads-in-flight is the limiter). Per-pair: shfl(p) +
//      ds_read(w) + lshl_add + 2 cvt_pk + 4 fma (~3.5 VALU/edge, was 5).
//      Epilogue: xor-32 merges edge-sets; 4ch/lane float4 math; xor1..16 proj.
// R23 retained: csr_build@1024, fused D1/D2, local bucket scans, u16 eps,
//      gemm2 deleted, MFMA gemm1 LDS-staged, fp8 e4m3 H1 rows, scalar agg2.
// Requires N < 65536 (16-bit packing). N = 50000.

#define LEAKY(x) ((x) > 0.f ? (x) : 0.2f * (x))

typedef float v2f __attribute__((ext_vector_type(2)));
typedef _Float16 f16x8 __attribute__((ext_vector_type(8)));
typedef __fp16 h16x2 __attribute__((ext_vector_type(2)));
typedef float f32x4 __attribute__((ext_vector_type(4)));

// ---------------- D0: zero control arrays ----------------

__global__ __launch_bounds__(256) void zero_kernel(int* __restrict__ bcnt,
                                                   int* __restrict__ bcur_rel,
                                                   int* __restrict__ off,
                                                   int B, int n, int Etot) {
  if (threadIdx.x <= (unsigned)B) {
    bcnt[threadIdx.x] = 0;
    bcur_rel[threadIdx.x] = 0;
  }
  if (threadIdx.x == 255) off[n] = Etot;
}

// ---------------- D1: wprep + bucket_cnt (fused, disjoint blocks) -----------

template <int VPT>
__global__ __launch_bounds__(256) void prep_cnt_kernel(const float* __restrict__ W1,
                                                       const float* __restrict__ W2,
                                                       const float* __restrict__ as2,
                                                       const float* __restrict__ ad2,
                                                       const float* __restrict__ lw,
                                                       unsigned short* __restrict__ Wp1,
                                                       float* __restrict__ vsrc2,
                                                       float* __restrict__ vdst2,
                                                       float* __restrict__ vlin,
                                                       const int* __restrict__ ei, int E, int n,
                                                       int* __restrict__ bc, int WB) {
  if ((int)blockIdx.x < WB) {
    int t = blockIdx.x * 256 + threadIdx.x;
    if (t < 16384) {
      int e = t;
      int i = e & 7;
      int c = (e >> 3) & 15;
      int g = (e >> 7) & 3;
      int kk = (e >> 9) & 3;
      int cn = e >> 11;
      int k = kk * 32 + g * 8 + i;
      int col = cn * 16 + c;
      __half h = __float2half(W1[k * 128 + col]);
      Wp1[e] = *(unsigned short*)&h;
    } else if (t < 16384 + 128) {
      int k = t - 16384;
      float a = 0.f, b = 0.f, s = 0.f;
      for (int cc = 0; cc < 64; ++cc) {
        float w = W2[k * 64 + cc];
        a = fmaf(w, as2[cc], a);
        b = fmaf(w, ad2[cc], b);
        s = fmaf(w, lw[cc], s);
      }
      vsrc2[k] = a;
      vdst2[k] = b;
      vlin[k] = s;
    }
    return;
  }
  // ---- bucket_cnt part ----
  __shared__ int lc[256];
  int t = threadIdx.x;
  lc[t] = 0;
  __syncthreads();
  int base = (blockIdx.x - WB) * (256 * VPT) + t;
  int tot = E + n;
#pragma unroll
  for (int u = 0; u < VPT; ++u) {
    int i = base + u * 256;
    if (i < tot) {
      int d = (i < E) ? ei[E + i] : (i - E);
      atomicAdd(&lc[d >> 8], 1);
    }
  }
  __syncthreads();
  if (lc[t]) atomicAdd(&bc[t], lc[t]);
}

// ---------------- D2: gemm1 + bucket_scatter (fused, concurrent) ------------

template <int VPT>
__global__ __launch_bounds__(256) void gemm_scatter_kernel(
    const float* __restrict__ X, const uint4* __restrict__ Wp,
    const float* __restrict__ a_src, const float* __restrict__ a_dst,
    unsigned char* __restrict__ Hout, float2* __restrict__ als, float2* __restrict__ ald,
    const int* __restrict__ ei, int E, int n,
    const int* __restrict__ bcnt, int* __restrict__ bcur_rel,
    unsigned* __restrict__ entries, int B, int GB) {
  if ((int)blockIdx.x < GB) {
    // ================= gemm1 =================
    __shared__ float Xl[32 * 132];
    __shared__ float lgt[2][2][2][16];
    int t = threadIdx.x;
    int wave = t >> 6, lane = t & 63;
    int wm = wave >> 1, wn = wave & 1;
    int g = lane >> 4, c = lane & 15;
    int nb0 = blockIdx.x * 32;

    {
      const float4* Xg = (const float4*)X;
      float4* Xs = (float4*)Xl;
#pragma unroll
      for (int u = 0; u < 4; ++u) {
        int idx = u * 256 + t;
        int r = idx >> 5, c4 = idx & 31;
        int row = nb0 + r;
        int rc = row < n ? row : (n - 1);
        Xs[r * 33 + c4] = Xg[(size_t)rc * 32 + c4];
      }
    }
    __syncthreads();

    f16x8 af[4];
    const float* xr = Xl + (wm * 16 + c) * 132 + g * 8;
#pragma unroll
    for (int kk = 0; kk < 4; ++kk) {
      float4 x0 = *(const float4*)(xr + kk * 32);
      float4 x1 = *(const float4*)(xr + kk * 32 + 4);
      union { f16x8 v; h16x2 p[4]; } A;
      A.p[0] = __builtin_amdgcn_cvt_pkrtz(x0.x, x0.y);
      A.p[1] = __builtin_amdgcn_cvt_pkrtz(x0.z, x0.w);
      A.p[2] = __builtin_amdgcn_cvt_pkrtz(x1.x, x1.y);
      A.p[3] = __builtin_amdgcn_cvt_pkrtz(x1.z, x1.w);
      af[kk] = A.v;
    }

    f32x4 acc[4];
    f32x4 z = {0.f, 0.f, 0.f, 0.f};
#pragma unroll
    for (int cn = 0; cn < 4; ++cn) acc[cn] = z;
#pragma unroll
    for (int cn = 0; cn < 4; ++cn) {
      int cng = wn * 4 + cn;
#pragma unroll
      for (int kk = 0; kk < 4; ++kk) {
        union { uint4 u; f16x8 v; } Bf;
        Bf.u = Wp[(cng * 4 + kk) * 64 + lane];
        acc[cn] = __builtin_amdgcn_mfma_f32_16x16x32_f16(af[kk], Bf.v, acc[cn], 0, 0, 0);
      }
    }

    float asv[4], adv[4];
#pragma unroll
    for (int cn = 0; cn < 4; ++cn) {
      int col_l = wn * 64 + cn * 16 + c;
      asv[cn] = a_src[col_l];
      adv[cn] = a_dst[col_l];
    }
    float ps[4] = {0.f, 0.f, 0.f, 0.f};
    float pd[4] = {0.f, 0.f, 0.f, 0.f};
#pragma unroll
    for (int cn = 0; cn < 4; ++cn) {
#pragma unroll
      for (int r = 0; r < 4; ++r) {
        float v = acc[cn][r];
        ps[r] = fmaf(v, asv[cn], ps[r]);
        pd[r] = fmaf(v, adv[cn], pd[r]);
        int noder = nb0 + wm * 16 + g * 4 + r;
        int colg = wn * 64 + cn * 16 + c;
        if (noder < n) {
          int b8 = __builtin_amdgcn_cvt_pk_fp8_f32(v, v, 0, false);
          Hout[(size_t)noder * 128 + colg] = (unsigned char)(b8 & 0xff);
        }
      }
    }
#pragma unroll
    for (int r = 0; r < 4; ++r) {
#pragma unroll
      for (int m = 1; m <= 8; m <<= 1) {
        ps[r] += __shfl_xor(ps[r], m, 64);
        pd[r] += __shfl_xor(pd[r], m, 64);
      }
    }
    if (c == 0) {
#pragma unroll
      for (int r = 0; r < 4; ++r) {
        lgt[wm][wn][0][g * 4 + r] = ps[r];
        lgt[wm][wn][1][g * 4 + r] = pd[r];
      }
    }
    __syncthreads();
    if (t < 32) {
      int wmm = t >> 4, row = t & 15;
      int node = nb0 + wmm * 16 + row;
      if (node < n) {
        als[node] = make_float2(lgt[wmm][0][0][row], lgt[wmm][1][0][row]);
        ald[node] = make_float2(lgt[wmm][0][1][row], lgt[wmm][1][1][row]);
      }
    }
    return;
  }
  // ================= bucket_scatter =================
  __shared__ int lc[256];
  __shared__ int lbase[256];
  __shared__ int bscan[256];
  int t = threadIdx.x;
  lc[t] = 0;
  int v = (t < B) ? bcnt[t] : 0;
  bscan[t] = v;
  __syncthreads();
  for (int s = 1; s < 256; s <<= 1) {
    int a = (t >= s) ? bscan[t - s] : 0;
    __syncthreads();
    bscan[t] += a;
    __syncthreads();
  }
  int excl = bscan[t] - v;

  int base = (blockIdx.x - GB) * (256 * VPT) + t;
  int tot = E + n;
  int bb[VPT], ll[VPT];
  unsigned pk[VPT];
#pragma unroll
  for (int u = 0; u < VPT; ++u) {
    int i = base + u * 256;
    bb[u] = -1;
    if (i < tot) {
      int s, d;
      if (i < E) { s = ei[i]; d = ei[E + i]; }
      else       { s = d = i - E; }
      int b = d >> 8;
      bb[u] = b;
      ll[u] = atomicAdd(&lc[b], 1);
      pk[u] = (unsigned)s | ((unsigned)(d & 255) << 16);
    }
  }
  __syncthreads();
  if (lc[t]) lbase[t] = excl + atomicAdd(&bcur_rel[t], lc[t]);
  __syncthreads();
#pragma unroll
  for (int u = 0; u < VPT; ++u)
    if (bb[u] >= 0) entries[lbase[bb[u]] + ll[u]] = pk[u];
}

// ---------------- D3: csr_build at 1024 threads ----------------

__global__ __launch_bounds__(1024) void csr_build_kernel(const unsigned* __restrict__ entries,
                                                         const int* __restrict__ bcnt,
                                                         int* __restrict__ off,
                                                         unsigned short* __restrict__ eps,
                                                         int n, int B) {
  __shared__ int bscan[256];
  __shared__ int hist[256];
  __shared__ int scn[256];
  __shared__ int cur[256];
  int b = blockIdx.x, t = threadIdx.x;
  if (t < 256) bscan[t] = (t < B) ? bcnt[t] : 0;
  __syncthreads();
  for (int s = 1; s < 256; s <<= 1) {
    int a = (t >= (unsigned)s && t < 256) ? bscan[t - s] : 0;
    __syncthreads();
    if (t < 256) bscan[t] += a;
    __syncthreads();
  }
  int k0 = (b == 0) ? 0 : bscan[b - 1];
  int k1 = bscan[b];

  if (t < 256) hist[t] = 0;
  __syncthreads();
  for (int k = k0 + t; k < k1; k += 1024) atomicAdd(&hist[(entries[k] >> 16) & 255], 1);
  __syncthreads();
  int hv = (t < 256) ? hist[t] : 0;
  if (t < 256) scn[t] = hv;
  __syncthreads();
  for (int s = 1; s < 256; s <<= 1) {
    int a = (t >= (unsigned)s && t < 256) ? scn[t - s] : 0;
    __syncthreads();
    if (t < 256) scn[t] += a;
    __syncthreads();
  }
  if (t < 256) {
    int excl = scn[t] - hv;
    int d = (b << 8) + t;
    if (d < n) off[d] = k0 + excl;
    cur[t] = k0 + excl;
  }
  __syncthreads();
  for (int k = k0 + t; k < k1; k += 1024) {
    unsigned e = entries[k];
    unsigned dl = (e >> 16) & 255;
    int p = atomicAdd(&cur[dl], 1);
    eps[p] = (unsigned short)(e & 0xffffu);
  }
}

// ---------------- D4: agg1 (2 edges per wave-load) ----------------

__global__ __launch_bounds__(256) void agg1_kernel(const unsigned char* __restrict__ Hb8,
                                                   const float2* __restrict__ als,
                                                   const float2* __restrict__ ald,
                                                   const unsigned short* __restrict__ eps,
                                                   const int* __restrict__ off,
                                                   const float* __restrict__ b1,
                                                   const float* __restrict__ vsrc2,
                                                   const float* __restrict__ vdst2,
                                                   const float* __restrict__ vlin,
                                                   float2* __restrict__ gsrc,
                                                   float* __restrict__ adst2, int n) {
  __shared__ float wlds[4][128];
  int wid = (blockIdx.x * 256 + threadIdx.x) >> 6;
  int lane = threadIdx.x & 63;
  if (wid >= n) return;
  wid = __builtin_amdgcn_readfirstlane(wid);
  int wslot = (threadIdx.x >> 6) & 3;
  int sel = lane >> 5;      // which edge of the pair this half-wave handles
  int c31 = lane & 31;      // dword (4 fp8 ch) within the row
  int head = c31 >> 4;      // head of these channels
  int k0 = off[wid], k1 = off[wid + 1];
  const unsigned* Hd = (const unsigned*)Hb8;  // row = 32 dwords
  float2 advv = ald[wid];
  int wbase = head * 64 + sel;  // LDS weight index base

  float a0 = 0.f, a1 = 0.f, a2 = 0.f, a3 = 0.f, den0 = 0.f, den1 = 0.f;

  for (int kb = k0; kb < k1; kb += 64) {
    int rem = min(k1 - kb, 64);
    int e = kb + (lane < rem ? lane : rem - 1);
    unsigned pp = eps[e];
    float2 l = als[pp];
    float g0 = __expf(LEAKY(l.x + advv.x));
    float g1 = __expf(LEAKY(l.y + advv.y));
    bool ok = lane < rem;
    wlds[wslot][lane] = ok ? g0 : 0.f;       // phantom edges get w = 0
    wlds[wslot][64 + lane] = ok ? g1 : 0.f;
    if (ok) { den0 += g0; den1 += g1; }
    int npair = (rem + 1) >> 1;

#define PAIR1(qq)                                                                   \
  {                                                                                 \
    unsigned p = (unsigned)__shfl((int)pp, ((qq) << 1) + sel, 64);                  \
    float w = wlds[wslot][wbase + ((qq) << 1)];                                     \
    unsigned hv = Hd[p * 32u + (unsigned)c31];                                      \
    v2f lo = __builtin_amdgcn_cvt_pk_f32_fp8((int)hv, false);                       \
    v2f hi = __builtin_amdgcn_cvt_pk_f32_fp8((int)hv, true);                        \
    a0 = fmaf(lo.x, w, a0);                                                         \
    a1 = fmaf(lo.y, w, a1);                                                         \
    a2 = fmaf(hi.x, w, a2);                                                         \
    a3 = fmaf(hi.y, w, a3);                                                         \
  }

    int nb = npair >> 3;
    for (int b = 0; b < nb; ++b) {
      int qb = b << 3;
#pragma unroll
      for (int q = 0; q < 8; ++q) PAIR1(qb + q);
    }
    for (int q = nb << 3; q < npair; ++q) PAIR1(q);
#undef PAIR1
  }

  // merge the two edge-sets (halves computed disjoint edges, same channels)
  a0 += __shfl_xor(a0, 32, 64);
  a1 += __shfl_xor(a1, 32, 64);
  a2 += __shfl_xor(a2, 32, 64);
  a3 += __shfl_xor(a3, 32, 64);
  // den butterfly (per-lane partials over distinct edges)
#pragma unroll
  for (int m = 1; m <= 32; m <<= 1) {
    den0 += __shfl_xor(den0, m, 64);
    den1 += __shfl_xor(den1, m, 64);
  }
  float den = head ? den1 : den0;

  // elu(out + b1), then project onto the three layer-2 vectors (4 ch/lane).
  float inv = 1.f / (den + 1e-16f);
  float4 bv = ((const float4*)b1)[c31];
  float r0 = a0 * inv + bv.x;
  float r1 = a1 * inv + bv.y;
  float r2 = a2 * inv + bv.z;
  float r3 = a3 * inv + bv.w;
  r0 = r0 > 0.f ? r0 : (__expf(r0) - 1.f);
  r1 = r1 > 0.f ? r1 : (__expf(r1) - 1.f);
  r2 = r2 > 0.f ? r2 : (__expf(r2) - 1.f);
  r3 = r3 > 0.f ? r3 : (__expf(r3) - 1.f);
  float4 vs = ((const float4*)vsrc2)[c31];
  float4 vd = ((const float4*)vdst2)[c31];
  float4 vl = ((const float4*)vlin)[c31];
  float ps = r0 * vs.x + r1 * vs.y + r2 * vs.z + r3 * vs.w;
  float pd = r0 * vd.x + r1 * vd.y + r2 * vd.z + r3 * vd.w;
  float sv = r0 * vl.x + r1 * vl.y + r2 * vl.z + r3 * vl.w;
  // channels live once per 32-lane half (halves duplicate) -> xor 1..16 only
#pragma unroll
  for (int m = 1; m <= 16; m <<= 1) {
    ps += __shfl_xor(ps, m, 64);
    pd += __shfl_xor(pd, m, 64);
    sv += __shfl_xor(sv, m, 64);
  }
  if (lane == 0) {
    gsrc[wid] = make_float2(ps, sv);
    adst2[wid] = pd;
  }
}

// ---------------- D5: agg2 ----------------

__global__ __launch_bounds__(256) void agg2_kernel(const float2* __restrict__ gsrc,
                                                   const float* __restrict__ adst2,
                                                   const unsigned short* __restrict__ eps,
                                                   const int* __restrict__ off,
                                                   const float* __restrict__ b2,
                                                   const float* __restrict__ lin_w,
                                                   const float* __restrict__ lin_b,
                                                   float* __restrict__ out, int n) {
  int wid = (blockIdx.x * 256 + threadIdx.x) >> 6;
  int lane = threadIdx.x & 63;
  if (wid >= n) return;
  wid = __builtin_amdgcn_readfirstlane(wid);
  int k0 = off[wid], k1 = off[wid + 1];
  float adv = adst2[wid];

  float num = 0.f, den = 0.f;
  for (int kb = k0; kb < k1; kb += 64) {
    int e = kb + lane;
    bool ok = e < k1;
    unsigned pp = eps[ok ? e : k0];
    float2 g = gsrc[pp];
    float w = ok ? __expf(LEAKY(g.x + adv)) : 0.f;
    num = fmaf(w, g.y, num);
    den += w;
  }
  float bt = b2[lane] * lin_w[lane];
#pragma unroll
  for (int m = 1; m <= 32; m <<= 1) {
    num += __shfl_xor(num, m, 64);
    den += __shfl_xor(den, m, 64);
    bt  += __shfl_xor(bt, m, 64);
  }
  if (lane == 0) out[wid] = num / (den + 1e-16f) + bt + lin_b[0];
}

// ---------------- launcher ----------------

static inline size_t alignup(size_t v) { return (v + 255) & ~(size_t)255; }

extern "C" void kernel_launch(void* const* d_in, const int* in_sizes, int n_in,
                              void* d_out, int out_size, void* d_ws, size_t ws_size,
                              hipStream_t stream) {
  const float* x   = (const float*)d_in[0];
  const int*   ei  = (const int*)d_in[1];
  const float* W1  = (const float*)d_in[2];
  const float* as1 = (const float*)d_in[3];
  const float* ad1 = (const float*)d_in[4];
  const float* b1  = (const float*)d_in[5];
  const float* W2  = (const float*)d_in[6];
  const float* as2 = (const float*)d_in[7];
  const float* ad2 = (const float*)d_in[8];
  const float* b2  = (const float*)d_in[9];
  const float* lw  = (const float*)d_in[10];
  const float* lb  = (const float*)d_in[11];
  float* out = (float*)d_out;

  const int N = out_size;          // 50000
  const int E = in_sizes[1] / 2;   // 1600000
  const int Etot = E + N;
  const int B = (N + 255) >> 8;    // 196 buckets

  char* p = (char*)d_ws;
  int* bcnt = (int*)p;  p += alignup((size_t)(B + 1) * 4);
  int* bcur_rel = (int*)p; p += alignup((size_t)(B + 1) * 4);
  unsigned* entries = (unsigned*)p; p += alignup((size_t)Etot * 4);
  int* off  = (int*)p;  p += alignup((size_t)(N + 1) * 4);
  unsigned short* eps = (unsigned short*)p; p += alignup((size_t)Etot * 2);
  float2* als = (float2*)p; p += alignup((size_t)N * 8);
  float2* ald = (float2*)p; p += alignup((size_t)N * 8);
  float2* gsrc = (float2*)p; p += alignup((size_t)N * 8);
  float* adst2 = (float*)p; p += alignup((size_t)N * 4);
  unsigned char* h1b = (unsigned char*)p; p += alignup((size_t)N * 128);
  unsigned short* wp1 = (unsigned short*)p; p += alignup((size_t)16384 * 2);
  float* vsrc2 = (float*)p; p += alignup((size_t)128 * 4);
  float* vdst2 = (float*)p; p += alignup((size_t)128 * 4);
  float* vlin  = (float*)p; p += alignup((size_t)128 * 4);

  constexpr int VPT = 8;
  int egrid = (Etot + 256 * VPT - 1) / (256 * VPT);
  constexpr int WB = 65;                 // wprep blocks
  int GB = (N + 31) / 32;                // gemm1 blocks

  zero_kernel<<<1, 256, 0, stream>>>(bcnt, bcur_rel, off, B, N, Etot);
  prep_cnt_kernel<VPT><<<WB + egrid, 256, 0, stream>>>(
      W1, W2, as2, ad2, lw, wp1, vsrc2, vdst2, vlin, ei, E, N, bcnt, WB);
  gemm_scatter_kernel<VPT><<<GB + egrid, 256, 0, stream>>>(
      x, (const uint4*)wp1, as1, ad1, h1b, als, ald,
      ei, E, N, bcnt, bcur_rel, entries, B, GB);
  csr_build_kernel<<<B, 1024, 0, stream>>>(entries, bcnt, off, eps, N, B);

  agg1_kernel<<<(N + 3) / 4, 256, 0, stream>>>(h1b, als, ald, eps, off, b1,
                                               vsrc2, vdst2, vlin, gsrc, adst2, N);
  agg2_kernel<<<(N + 3) / 4, 256, 0, stream>>>(gsrc, adst2, eps, off, b2, lw, lb, out, N);
}